// Round 1
// baseline (5731.926 us; speedup 1.0000x reference)
//
#include <hip/hip_runtime.h>

// GCN ensemble: out = gcn(relu(gcn(x,ei,W0,b0)),ei,W2,b2) + gcn(relu(gcn(x,ein,W1,b1)),ein,W3,b3)
// Strategy:
//   layer1: aggregate x (128f) FIRST, then GEMM  (A(xW) == (Ax)W)
//   layer2: GEMM first (256->128), then aggregate 128f
//   both branches accumulate into d_out directly; out pre-init with b2+b3.

#define NN 50000
#define EE 800000

__global__ void k_fill1(float* p, int n) {
    int i = blockIdx.x * blockDim.x + threadIdx.x;
    if (i < n) p[i] = 1.0f;
}

__global__ void k_count_deg(const int* __restrict__ dst_a, const int* __restrict__ dst_b,
                            float* deg_a, float* deg_b, int e) {
    int i = blockIdx.x * blockDim.x + threadIdx.x;
    if (i < e) {
        atomicAdd(deg_a + dst_a[i], 1.0f);
        atomicAdd(deg_b + dst_b[i], 1.0f);
    }
}

__global__ void k_rsqrt(float* p, int n) {
    int i = blockIdx.x * blockDim.x + threadIdx.x;
    if (i < n) p[i] = rsqrtf(p[i]);
}

// t128[i][:] = x[i][:] * dinv[i]^2   (float4 over N*32)
__global__ void k_self_init(const float4* __restrict__ x4, const float* __restrict__ dinv,
                            float4* __restrict__ o4, int n32) {
    int i = blockIdx.x * blockDim.x + threadIdx.x;
    if (i < n32) {
        float s = dinv[i >> 5];
        s = s * s;
        float4 v = x4[i];
        o4[i] = make_float4(v.x * s, v.y * s, v.z * s, v.w * s);
    }
}

// out[i][:] += h[i][:] * dinv[i]^2
__global__ void k_self_add(const float4* __restrict__ h4, const float* __restrict__ dinv,
                           float4* __restrict__ out4, int n32) {
    int i = blockIdx.x * blockDim.x + threadIdx.x;
    if (i < n32) {
        float s = dinv[i >> 5];
        s = s * s;
        float4 v = h4[i];
        float4 o = out4[i];
        o.x += v.x * s; o.y += v.y * s; o.z += v.z * s; o.w += v.w * s;
        out4[i] = o;
    }
}

// out[i][f] = b2[f] + b3[f]
__global__ void k_out_bias(const float* __restrict__ b2, const float* __restrict__ b3,
                           float* __restrict__ out, int total) {
    int i = blockIdx.x * blockDim.x + threadIdx.x;
    if (i < total) {
        int f = i & 127;
        out[i] = b2[f] + b3[f];
    }
}

// scatter: out[dst] += h[src] * dinv[src]*dinv[dst], 128 feats, 32 lanes/edge
__global__ void k_scatter128(const float* __restrict__ h, const int* __restrict__ src,
                             const int* __restrict__ dst, const float* __restrict__ dinv,
                             float* __restrict__ out, int e) {
    int g = blockIdx.x * blockDim.x + threadIdx.x;
    int edge = g >> 5;
    int lane = g & 31;
    if (edge < e) {
        int s = src[edge], d = dst[edge];
        float nrm = dinv[s] * dinv[d];
        float4 v = *(const float4*)(h + (size_t)s * 128 + lane * 4);
        float* o = out + (size_t)d * 128 + lane * 4;
        atomicAdd(o + 0, v.x * nrm);
        atomicAdd(o + 1, v.y * nrm);
        atomicAdd(o + 2, v.z * nrm);
        atomicAdd(o + 3, v.w * nrm);
    }
}

// C[n,Co] = A[n,K] @ W[K,Co] (+bias)(+relu). 64x64 tile, BK=16, 256 thr, 4x4/thread.
__global__ __launch_bounds__(256) void k_gemm(
    const float* __restrict__ A, const float* __restrict__ W,
    const float* __restrict__ bias, float* __restrict__ C,
    int n, int K, int Co, int do_relu) {
    __shared__ float As[16][68];  // [k][m], pad 4 keeps 16B-aligned rows, breaks conflicts
    __shared__ float Bs[16][68];  // [k][co]

    const int tid = threadIdx.x;
    const int tx = tid & 15;
    const int ty = tid >> 4;
    const int bn = blockIdx.x * 64;
    const int bm = blockIdx.y * 64;

    const int la_m = tid >> 2;        // 0..63
    const int la_k = (tid & 3) * 4;   // 0,4,8,12
    const int lb_k = tid >> 4;        // 0..15
    const int lb_n = (tid & 15) * 4;  // 0..60

    float acc[4][4] = {};

    for (int k0 = 0; k0 < K; k0 += 16) {
        int arow = bm + la_m;
        float4 av = make_float4(0.f, 0.f, 0.f, 0.f);
        if (arow < n) av = *(const float4*)(A + (size_t)arow * K + k0 + la_k);
        As[la_k + 0][la_m] = av.x;
        As[la_k + 1][la_m] = av.y;
        As[la_k + 2][la_m] = av.z;
        As[la_k + 3][la_m] = av.w;
        *(float4*)&Bs[lb_k][lb_n] = *(const float4*)(W + (size_t)(k0 + lb_k) * Co + bn + lb_n);
        __syncthreads();
#pragma unroll
        for (int k = 0; k < 16; ++k) {
            float4 a = *(const float4*)&As[k][ty * 4];
            float4 b = *(const float4*)&Bs[k][tx * 4];
            float ar[4] = {a.x, a.y, a.z, a.w};
            float br[4] = {b.x, b.y, b.z, b.w};
#pragma unroll
            for (int i = 0; i < 4; ++i)
#pragma unroll
                for (int j = 0; j < 4; ++j) acc[i][j] += ar[i] * br[j];
        }
        __syncthreads();
    }

    float4 bv = make_float4(0.f, 0.f, 0.f, 0.f);
    if (bias) bv = *(const float4*)(bias + bn + tx * 4);
#pragma unroll
    for (int i = 0; i < 4; ++i) {
        int row = bm + ty * 4 + i;
        if (row >= n) break;
        float4 o;
        o.x = acc[i][0] + bv.x;
        o.y = acc[i][1] + bv.y;
        o.z = acc[i][2] + bv.z;
        o.w = acc[i][3] + bv.w;
        if (do_relu) {
            o.x = fmaxf(o.x, 0.f); o.y = fmaxf(o.y, 0.f);
            o.z = fmaxf(o.z, 0.f); o.w = fmaxf(o.w, 0.f);
        }
        *(float4*)(C + (size_t)row * Co + bn + tx * 4) = o;
    }
}

extern "C" void kernel_launch(void* const* d_in, const int* in_sizes, int n_in,
                              void* d_out, int out_size, void* d_ws, size_t ws_size,
                              hipStream_t stream) {
    const float* x   = (const float*)d_in[0];
    const int*   ei_a = (const int*)d_in[1];
    const int*   ei_b = (const int*)d_in[2];
    const float* W0 = (const float*)d_in[3];
    const float* b0 = (const float*)d_in[4];
    const float* W1 = (const float*)d_in[5];
    const float* b1 = (const float*)d_in[6];
    const float* W2 = (const float*)d_in[7];
    const float* b2 = (const float*)d_in[8];
    const float* W3 = (const float*)d_in[9];
    const float* b3 = (const float*)d_in[10];
    float* out = (float*)d_out;

    const int n = in_sizes[0] / 128;   // 50000
    const int e = in_sizes[1] / 2;     // 800000

    float* ws     = (float*)d_ws;
    float* dinv_a = ws;                 // n
    float* dinv_b = ws + n;             // n
    float* t128   = ws + 2 * n;         // n*128
    float* t256   = ws + 2 * n + 128 * n;  // n*256

    const int B = 256;

    // degrees -> dinv (deg_a,deg_b contiguous)
    k_fill1<<<(2 * n + B - 1) / B, B, 0, stream>>>(dinv_a, 2 * n);
    k_count_deg<<<(e + B - 1) / B, B, 0, stream>>>(ei_a + e, ei_b + e, dinv_a, dinv_b, e);
    k_rsqrt<<<(2 * n + B - 1) / B, B, 0, stream>>>(dinv_a, 2 * n);

    // out = b2 + b3
    k_out_bias<<<(n * 128 + B - 1) / B, B, 0, stream>>>(b2, b3, out, n * 128);

    for (int br = 0; br < 2; ++br) {
        const int* ei    = br == 0 ? ei_a : ei_b;
        const float* Wl1 = br == 0 ? W0 : W1;
        const float* bl1 = br == 0 ? b0 : b1;
        const float* Wl2 = br == 0 ? W2 : W3;
        const float* dinv = br == 0 ? dinv_a : dinv_b;

        // t128 = x*dinv^2 ; t128 += scatter(x)
        k_self_init<<<(n * 32 + B - 1) / B, B, 0, stream>>>((const float4*)x, dinv,
                                                            (float4*)t128, n * 32);
        k_scatter128<<<(e * 32 + B - 1) / B, B, 0, stream>>>(x, ei, ei + e, dinv, t128, e);

        // t256 = relu(t128 @ W[128,256] + b)
        {
            dim3 grid(256 / 64, (n + 63) / 64);
            k_gemm<<<grid, B, 0, stream>>>(t128, Wl1, bl1, t256, n, 128, 256, 1);
        }
        // t128 = t256 @ W[256,128]   (no bias: b2+b3 already in out)
        {
            dim3 grid(128 / 64, (n + 63) / 64);
            k_gemm<<<grid, B, 0, stream>>>(t256, Wl2, nullptr, t128, n, 256, 128, 0);
        }

        // out += t128*dinv^2 ; out += scatter(t128)
        k_self_add<<<(n * 32 + B - 1) / B, B, 0, stream>>>((const float4*)t128, dinv,
                                                           (float4*)out, n * 32);
        k_scatter128<<<(e * 32 + B - 1) / B, B, 0, stream>>>(t128, ei, ei + e, dinv, out, e);
    }
}

// Round 2
// 720.061 us; speedup vs baseline: 7.9603x; 7.9603x over previous
//
#include <hip/hip_runtime.h>

// GCN ensemble, pull-based (CSR gather) formulation.
//   layer1: t128 = dinv_d * sum(dinv_s * x[s]) + dinv_d^2 * x[d]      (aggregate-then-GEMM)
//   layer2: out += dinv_d * sum(dinv_s * h[s]) + dinv_d^2 * h[d]      (GEMM-then-aggregate)
// CSR per edge list built fresh every call (ws is re-poisoned). Each CSR used twice.

// ---------- CSR build ----------

__global__ void k_hist(const int* __restrict__ dst_a, const int* __restrict__ dst_b,
                       int* cnt_a, int* cnt_b, int e) {
    int i = blockIdx.x * blockDim.x + threadIdx.x;
    if (i < e) {
        atomicAdd(cnt_a + dst_a[i], 1);
        atomicAdd(cnt_b + dst_b[i], 1);
    }
}

// dinv[i] = rsqrt(cnt[i] + 1), over 2n (cnt_a|cnt_b contiguous, dinv_a|dinv_b contiguous)
__global__ void k_dinv(const int* __restrict__ cnt, float* __restrict__ dinv, int n2) {
    int i = blockIdx.x * blockDim.x + threadIdx.x;
    if (i < n2) dinv[i] = rsqrtf((float)cnt[i] + 1.0f);
}

// exclusive scan of cnt[0..n) into off[0..n); partials[b] = block total. 256 blocks x 256.
__global__ void k_scan1(const int* __restrict__ cnt, int* __restrict__ off,
                        int* __restrict__ partials, int n) {
    __shared__ int s[256];
    int t = threadIdx.x, b = blockIdx.x;
    int i = b * 256 + t;
    int v = (i < n) ? cnt[i] : 0;
    s[t] = v;
    __syncthreads();
    for (int o = 1; o < 256; o <<= 1) {
        int x = 0;
        if (t >= o) x = s[t - o];
        __syncthreads();
        s[t] += x;
        __syncthreads();
    }
    if (i < n) off[i] = s[t] - v;  // exclusive
    if (t == 255) partials[b] = s[255];
}

__global__ void k_scan2(int* partials) {  // 1 block x 256, exclusive scan in place
    __shared__ int s[256];
    int t = threadIdx.x;
    int v = partials[t];
    s[t] = v;
    __syncthreads();
    for (int o = 1; o < 256; o <<= 1) {
        int x = 0;
        if (t >= o) x = s[t - o];
        __syncthreads();
        s[t] += x;
        __syncthreads();
    }
    partials[t] = s[t] - v;
}

__global__ void k_scan3(int* __restrict__ off, const int* __restrict__ partials, int n, int e) {
    int i = blockIdx.x * blockDim.x + threadIdx.x;
    if (i < n) off[i] += partials[i >> 8];
    if (i == 0) off[n] = e;
}

// ent[off[dst] + running] = (src, dinv[src])
__global__ void k_fill_csr(const int* __restrict__ src, const int* __restrict__ dst,
                           const int* __restrict__ off, int* __restrict__ cnt,
                           const float* __restrict__ dinv, int2* __restrict__ ent, int e) {
    int i = blockIdx.x * blockDim.x + threadIdx.x;
    if (i < e) {
        int d = dst[i], s = src[i];
        int pos = off[d] + atomicAdd(cnt + d, 1);
        ent[pos] = make_int2(s, __float_as_int(dinv[s]));
    }
}

// ---------- aggregation (pull) ----------
// one wave (64 lanes) per node, lane handles feats [2l,2l+1].
// out[i] (=acc? += : =) dinv[i]*sum_j w_j*h[src_j] + dinv[i]^2*h[i]
__global__ __launch_bounds__(256) void k_gather128(
    const float* __restrict__ h, const int* __restrict__ off, const int2* __restrict__ ent,
    const float* __restrict__ dinv, float* __restrict__ out, int n, int accumulate) {
    int node = (blockIdx.x * 256 + threadIdx.x) >> 6;
    int lane = threadIdx.x & 63;
    if (node >= n) return;
    int beg = off[node], end = off[node + 1];
    const int f = lane * 2;
    float ax = 0.f, ay = 0.f;
    int j = beg;
    // 2-deep unroll for a little MLP
    for (; j + 2 <= end; j += 2) {
        int2 e0 = ent[j], e1 = ent[j + 1];
        float w0 = __int_as_float(e0.y), w1 = __int_as_float(e1.y);
        float2 v0 = *(const float2*)(h + (size_t)e0.x * 128 + f);
        float2 v1 = *(const float2*)(h + (size_t)e1.x * 128 + f);
        ax += w0 * v0.x + w1 * v1.x;
        ay += w0 * v0.y + w1 * v1.y;
    }
    if (j < end) {
        int2 e0 = ent[j];
        float w0 = __int_as_float(e0.y);
        float2 v0 = *(const float2*)(h + (size_t)e0.x * 128 + f);
        ax += w0 * v0.x;
        ay += w0 * v0.y;
    }
    float di = dinv[node];
    float2 sv = *(const float2*)(h + (size_t)node * 128 + f);
    float vx = di * ax + di * di * sv.x;
    float vy = di * ay + di * di * sv.y;
    float* o = out + (size_t)node * 128 + f;
    if (accumulate) {
        o[0] += vx;
        o[1] += vy;
    } else {
        o[0] = vx;
        o[1] = vy;
    }
}

// out[i][f] = b2[f] + b3[f]
__global__ void k_out_bias(const float* __restrict__ b2, const float* __restrict__ b3,
                           float* __restrict__ out, int total) {
    int i = blockIdx.x * blockDim.x + threadIdx.x;
    if (i < total) {
        int f = i & 127;
        out[i] = b2[f] + b3[f];
    }
}

// ---------- GEMM ----------
// C[n,Co] = A[n,K] @ W[K,Co] (+bias)(+relu). 64x64 tile, BK=16, 256 thr, 4x4/thread.
__global__ __launch_bounds__(256) void k_gemm(
    const float* __restrict__ A, const float* __restrict__ W,
    const float* __restrict__ bias, float* __restrict__ C,
    int n, int K, int Co, int do_relu) {
    __shared__ float As[16][68];
    __shared__ float Bs[16][68];

    const int tid = threadIdx.x;
    const int tx = tid & 15;
    const int ty = tid >> 4;
    const int bn = blockIdx.x * 64;
    const int bm = blockIdx.y * 64;

    const int la_m = tid >> 2;
    const int la_k = (tid & 3) * 4;
    const int lb_k = tid >> 4;
    const int lb_n = (tid & 15) * 4;

    float acc[4][4] = {};

    for (int k0 = 0; k0 < K; k0 += 16) {
        int arow = bm + la_m;
        float4 av = make_float4(0.f, 0.f, 0.f, 0.f);
        if (arow < n) av = *(const float4*)(A + (size_t)arow * K + k0 + la_k);
        As[la_k + 0][la_m] = av.x;
        As[la_k + 1][la_m] = av.y;
        As[la_k + 2][la_m] = av.z;
        As[la_k + 3][la_m] = av.w;
        *(float4*)&Bs[lb_k][lb_n] = *(const float4*)(W + (size_t)(k0 + lb_k) * Co + bn + lb_n);
        __syncthreads();
#pragma unroll
        for (int k = 0; k < 16; ++k) {
            float4 a = *(const float4*)&As[k][ty * 4];
            float4 b = *(const float4*)&Bs[k][tx * 4];
            float ar[4] = {a.x, a.y, a.z, a.w};
            float br[4] = {b.x, b.y, b.z, b.w};
#pragma unroll
            for (int i = 0; i < 4; ++i)
#pragma unroll
                for (int j = 0; j < 4; ++j) acc[i][j] += ar[i] * br[j];
        }
        __syncthreads();
    }

    float4 bv = make_float4(0.f, 0.f, 0.f, 0.f);
    if (bias) bv = *(const float4*)(bias + bn + tx * 4);
#pragma unroll
    for (int i = 0; i < 4; ++i) {
        int row = bm + ty * 4 + i;
        if (row >= n) break;
        float4 o;
        o.x = acc[i][0] + bv.x;
        o.y = acc[i][1] + bv.y;
        o.z = acc[i][2] + bv.z;
        o.w = acc[i][3] + bv.w;
        if (do_relu) {
            o.x = fmaxf(o.x, 0.f); o.y = fmaxf(o.y, 0.f);
            o.z = fmaxf(o.z, 0.f); o.w = fmaxf(o.w, 0.f);
        }
        *(float4*)(C + (size_t)row * Co + bn + tx * 4) = o;
    }
}

extern "C" void kernel_launch(void* const* d_in, const int* in_sizes, int n_in,
                              void* d_out, int out_size, void* d_ws, size_t ws_size,
                              hipStream_t stream) {
    const float* x    = (const float*)d_in[0];
    const int*   ei_a = (const int*)d_in[1];
    const int*   ei_b = (const int*)d_in[2];
    const float* W0 = (const float*)d_in[3];
    const float* b0 = (const float*)d_in[4];
    const float* W1 = (const float*)d_in[5];
    const float* b1 = (const float*)d_in[6];
    const float* W2 = (const float*)d_in[7];
    const float* b2 = (const float*)d_in[8];
    const float* W3 = (const float*)d_in[9];
    const float* b3 = (const float*)d_in[10];
    float* out = (float*)d_out;

    const int n = in_sizes[0] / 128;  // 50000
    const int e = in_sizes[1] / 2;    // 800000

    // workspace layout
    float* ws     = (float*)d_ws;
    float* dinv_a = ws;                        // n   (dinv_a|dinv_b contiguous)
    float* t128   = ws + 2 * n;                // 128n
    float* t256   = t128 + 128 * (size_t)n;    // 256n
    int*   iw     = (int*)(t256 + 256 * (size_t)n);
    int*   cnt_a  = iw;                        // n   (cnt_a|cnt_b contiguous)
    int*   cnt_b  = iw + n;                    // n
    int*   off_a  = iw + 2 * n;                // n+1
    int*   off_b  = off_a + (n + 1);           // n+1
    int*   part   = off_b + (n + 1);           // 256
    int2*  ent_a  = (int2*)(part + 256);       // e
    int2*  ent_b  = ent_a + e;                 // e

    const int B = 256;

    // --- CSR build (both lists) ---
    hipMemsetAsync(cnt_a, 0, 2 * n * sizeof(int), stream);
    k_hist<<<(e + B - 1) / B, B, 0, stream>>>(ei_a + e, ei_b + e, cnt_a, cnt_b, e);
    k_dinv<<<(2 * n + B - 1) / B, B, 0, stream>>>(cnt_a, dinv_a, 2 * n);

    k_scan1<<<256, 256, 0, stream>>>(cnt_a, off_a, part, n);
    k_scan2<<<1, 256, 0, stream>>>(part);
    k_scan3<<<256, 256, 0, stream>>>(off_a, part, n, e);
    k_scan1<<<256, 256, 0, stream>>>(cnt_b, off_b, part, n);
    k_scan2<<<1, 256, 0, stream>>>(part);
    k_scan3<<<256, 256, 0, stream>>>(off_b, part, n, e);

    hipMemsetAsync(cnt_a, 0, 2 * n * sizeof(int), stream);
    k_fill_csr<<<(e + B - 1) / B, B, 0, stream>>>(ei_a, ei_a + e, off_a, cnt_a, dinv_a, ent_a, e);
    k_fill_csr<<<(e + B - 1) / B, B, 0, stream>>>(ei_b, ei_b + e, off_b, cnt_b, dinv_a + n, ent_b, e);

    // out = b2 + b3
    k_out_bias<<<(n * 128 + B - 1) / B, B, 0, stream>>>(b2, b3, out, n * 128);

    const int gather_grid = (n + 3) / 4;  // 4 waves (nodes) per 256-thr block
    for (int br = 0; br < 2; ++br) {
        const int*  off  = br == 0 ? off_a : off_b;
        const int2* ent  = br == 0 ? ent_a : ent_b;
        const float* dinv = br == 0 ? dinv_a : dinv_a + n;
        const float* Wl1 = br == 0 ? W0 : W1;
        const float* bl1 = br == 0 ? b0 : b1;
        const float* Wl2 = br == 0 ? W2 : W3;

        // t128 = A_norm(x)
        k_gather128<<<gather_grid, B, 0, stream>>>(x, off, ent, dinv, t128, n, 0);
        // t256 = relu(t128 @ W[128,256] + b)
        {
            dim3 grid(256 / 64, (n + 63) / 64);
            k_gemm<<<grid, B, 0, stream>>>(t128, Wl1, bl1, t256, n, 128, 256, 1);
        }
        // t128 = t256 @ W[256,128]
        {
            dim3 grid(128 / 64, (n + 63) / 64);
            k_gemm<<<grid, B, 0, stream>>>(t256, Wl2, nullptr, t128, n, 256, 128, 0);
        }
        // out += A_norm(t128)
        k_gather128<<<gather_grid, B, 0, stream>>>(t128, off, ent, dinv, out, n, 1);
    }
}

// Round 3
// 635.586 us; speedup vs baseline: 9.0183x; 1.1329x over previous
//
#include <hip/hip_runtime.h>

// GCN ensemble, CSR-gather + split-bf16 MFMA GEMMs.
//   gather1 (bf16 x) -> t128 packed(hi,lo)  -> gemm1 MFMA -> t256 packed(hi,lo)
//   gemm2 MFMA -> t128b bf16 -> gather2 accumulates fp32 into out (pre-init b2+b3)
// Split-bf16: v = hi + lo, products hi*hi + hi*lo + lo*hi  (error ~2^-16 rel).

typedef unsigned int uint;
typedef unsigned short ushort;
typedef __attribute__((ext_vector_type(8))) short bf8_t;
typedef __attribute__((ext_vector_type(4))) float f4_t;

__device__ inline ushort f2bf(float f) {
    uint u = __float_as_uint(f);
    return (ushort)((u + 0x7fff + ((u >> 16) & 1)) >> 16);
}
__device__ inline float bf2f(ushort h) { return __uint_as_float(((uint)h) << 16); }
__device__ inline uint pack_split(float f) {
    ushort hi = f2bf(f);
    ushort lo = f2bf(f - bf2f(hi));
    return (uint)hi | ((uint)lo << 16);
}

// ---------- CSR build ----------

__global__ void k_hist(const int* __restrict__ dst_a, const int* __restrict__ dst_b,
                       int* cnt_a, int* cnt_b, int e) {
    int i = blockIdx.x * blockDim.x + threadIdx.x;
    if (i < e) {
        atomicAdd(cnt_a + dst_a[i], 1);
        atomicAdd(cnt_b + dst_b[i], 1);
    }
}

__global__ void k_dinv(const int* __restrict__ cnt, float* __restrict__ dinv, int n2) {
    int i = blockIdx.x * blockDim.x + threadIdx.x;
    if (i < n2) dinv[i] = rsqrtf((float)cnt[i] + 1.0f);
}

__global__ void k_scan1(const int* __restrict__ cnt, int* __restrict__ off,
                        int* __restrict__ partials, int n) {
    __shared__ int s[256];
    int t = threadIdx.x, b = blockIdx.x;
    int i = b * 256 + t;
    int v = (i < n) ? cnt[i] : 0;
    s[t] = v;
    __syncthreads();
    for (int o = 1; o < 256; o <<= 1) {
        int x = 0;
        if (t >= o) x = s[t - o];
        __syncthreads();
        s[t] += x;
        __syncthreads();
    }
    if (i < n) off[i] = s[t] - v;
    if (t == 255) partials[b] = s[255];
}

__global__ void k_scan2(int* partials) {
    __shared__ int s[256];
    int t = threadIdx.x;
    int v = partials[t];
    s[t] = v;
    __syncthreads();
    for (int o = 1; o < 256; o <<= 1) {
        int x = 0;
        if (t >= o) x = s[t - o];
        __syncthreads();
        s[t] += x;
        __syncthreads();
    }
    partials[t] = s[t] - v;
}

__global__ void k_scan3(int* __restrict__ off, const int* __restrict__ partials, int n, int e) {
    int i = blockIdx.x * blockDim.x + threadIdx.x;
    if (i < n) off[i] += partials[i >> 8];
    if (i == 0) off[n] = e;
}

__global__ void k_fill_csr(const int* __restrict__ src, const int* __restrict__ dst,
                           const int* __restrict__ off, int* __restrict__ cnt,
                           const float* __restrict__ dinv, int2* __restrict__ ent, int e) {
    int i = blockIdx.x * blockDim.x + threadIdx.x;
    if (i < e) {
        int d = dst[i], s = src[i];
        int pos = off[d] + atomicAdd(cnt + d, 1);
        ent[pos] = make_int2(s, __float_as_int(dinv[s]));
    }
}

// ---------- conversions / packing ----------

// x fp32 [n,128] -> xb bf16 pairs as uint [n*64]
__global__ void k_cvt_xb(const float2* __restrict__ x2, uint* __restrict__ xbu, int n64) {
    int i = blockIdx.x * blockDim.x + threadIdx.x;
    if (i < n64) {
        float2 v = x2[i];
        xbu[i] = (uint)f2bf(v.x) | ((uint)f2bf(v.y) << 16);
    }
}

// W fp32 [K,N] -> Wp frag-packed: Wp[((kt*NT+nt)*64+lane)*8+j] = pack_split(W[k][n])
// kt=k/32, quad=(k%32)/8, j=k%8, nt=n/16, lane=quad*16+(n%16)
__global__ void k_pack_w(const float* __restrict__ W, uint* __restrict__ Wp, int K, int N) {
    int i = blockIdx.x * blockDim.x + threadIdx.x;
    if (i >= K * N) return;
    int k = i / N, nn = i - k * N;
    int kt = k >> 5, q = (k & 31) >> 3, j = k & 7;
    int nt = nn >> 4, ln = q * 16 + (nn & 15);
    int NT = N >> 4;
    Wp[(((size_t)(kt * NT + nt)) * 64 + ln) * 8 + j] = pack_split(W[i]);
}

__global__ void k_out_bias(const float* __restrict__ b2, const float* __restrict__ b3,
                           float* __restrict__ out, int total) {
    int i = blockIdx.x * blockDim.x + threadIdx.x;
    if (i < total) {
        int f = i & 127;
        out[i] = b2[f] + b3[f];
    }
}

// ---------- gathers (one wave per node, lane handles feats 2l,2l+1) ----------

// layer1: reads xb (bf16 pairs), writes t128 packed split uint
__global__ __launch_bounds__(256) void k_gather_l1(
    const uint* __restrict__ xbu, const int* __restrict__ off, const int2* __restrict__ ent,
    const float* __restrict__ dinv, uint* __restrict__ t128p, int n) {
    int node = (blockIdx.x * 256 + threadIdx.x) >> 6;
    int lane = threadIdx.x & 63;
    if (node >= n) return;
    int beg = off[node], end = off[node + 1];
    float ax = 0.f, ay = 0.f;
    int j = beg;
    for (; j + 2 <= end; j += 2) {
        int2 e0 = ent[j], e1 = ent[j + 1];
        float w0 = __int_as_float(e0.y), w1 = __int_as_float(e1.y);
        uint u0 = xbu[(size_t)e0.x * 64 + lane];
        uint u1 = xbu[(size_t)e1.x * 64 + lane];
        ax += w0 * bf2f((ushort)u0) + w1 * bf2f((ushort)u1);
        ay += w0 * bf2f((ushort)(u0 >> 16)) + w1 * bf2f((ushort)(u1 >> 16));
    }
    if (j < end) {
        int2 e0 = ent[j];
        float w0 = __int_as_float(e0.y);
        uint u0 = xbu[(size_t)e0.x * 64 + lane];
        ax += w0 * bf2f((ushort)u0);
        ay += w0 * bf2f((ushort)(u0 >> 16));
    }
    float di = dinv[node];
    uint us = xbu[(size_t)node * 64 + lane];
    float vx = di * ax + di * di * bf2f((ushort)us);
    float vy = di * ay + di * di * bf2f((ushort)(us >> 16));
    uint2 o;
    o.x = pack_split(vx);
    o.y = pack_split(vy);
    *(uint2*)(t128p + (size_t)node * 128 + lane * 2) = o;
}

// layer2: reads t128b (bf16 pairs), accumulates fp32 into out
__global__ __launch_bounds__(256) void k_gather_l2(
    const uint* __restrict__ hbu, const int* __restrict__ off, const int2* __restrict__ ent,
    const float* __restrict__ dinv, float* __restrict__ out, int n) {
    int node = (blockIdx.x * 256 + threadIdx.x) >> 6;
    int lane = threadIdx.x & 63;
    if (node >= n) return;
    int beg = off[node], end = off[node + 1];
    float ax = 0.f, ay = 0.f;
    int j = beg;
    for (; j + 2 <= end; j += 2) {
        int2 e0 = ent[j], e1 = ent[j + 1];
        float w0 = __int_as_float(e0.y), w1 = __int_as_float(e1.y);
        uint u0 = hbu[(size_t)e0.x * 64 + lane];
        uint u1 = hbu[(size_t)e1.x * 64 + lane];
        ax += w0 * bf2f((ushort)u0) + w1 * bf2f((ushort)u1);
        ay += w0 * bf2f((ushort)(u0 >> 16)) + w1 * bf2f((ushort)(u1 >> 16));
    }
    if (j < end) {
        int2 e0 = ent[j];
        float w0 = __int_as_float(e0.y);
        uint u0 = hbu[(size_t)e0.x * 64 + lane];
        ax += w0 * bf2f((ushort)u0);
        ay += w0 * bf2f((ushort)(u0 >> 16));
    }
    float di = dinv[node];
    uint us = hbu[(size_t)node * 64 + lane];
    float vx = di * ax + di * di * bf2f((ushort)us);
    float vy = di * ay + di * di * bf2f((ushort)(us >> 16));
    float2* o = (float2*)(out + (size_t)node * 128 + lane * 2);
    float2 cur = *o;
    cur.x += vx;
    cur.y += vy;
    *o = cur;
}

// ---------- MFMA GEMM ----------
// A packed split uint [n,K]; Wp frag-packed; block = 128x128 (4 waves 2x2), wave = 64x64.
// 16x16x32 bf16 MFMA. A frag: A[m=lane&15][k=quad*8+j]; C/D: col=lane&15,row=quad*4+reg.
template <int K, int NT_TOTAL, bool RELU_BIAS, bool OUT_SPLIT>
__global__ __launch_bounds__(256) void k_gemm_mfma(
    const uint* __restrict__ Ap, const uint* __restrict__ Wp,
    const float* __restrict__ bias, void* __restrict__ Cout, int n) {
    const int lane = threadIdx.x & 63;
    const int wave = threadIdx.x >> 6;
    const int l15 = lane & 15;
    const int quad = lane >> 4;
    const int m_base = blockIdx.y * 128 + (wave >> 1) * 64;
    const int n_base = blockIdx.x * 128 + (wave & 1) * 64;
    const int N = NT_TOTAL * 16;

    f4_t acc[4][4];
#pragma unroll
    for (int a = 0; a < 4; ++a)
#pragma unroll
        for (int b = 0; b < 4; ++b) acc[a][b] = (f4_t){0.f, 0.f, 0.f, 0.f};

#pragma unroll
    for (int kt = 0; kt < K / 32; ++kt) {
        bf8_t ahi[4], alo[4];
#pragma unroll
        for (int mi = 0; mi < 4; ++mi) {
            int row = m_base + mi * 16 + l15;
            uint4 u0 = {0, 0, 0, 0}, u1 = {0, 0, 0, 0};
            if (row < n) {
                const uint* p = Ap + (size_t)row * K + kt * 32 + quad * 8;
                u0 = *(const uint4*)p;
                u1 = *(const uint4*)(p + 4);
            }
            uint ua[8] = {u0.x, u0.y, u0.z, u0.w, u1.x, u1.y, u1.z, u1.w};
#pragma unroll
            for (int j = 0; j < 8; ++j) {
                ahi[mi][j] = (short)(ua[j] & 0xffff);
                alo[mi][j] = (short)(ua[j] >> 16);
            }
        }
#pragma unroll
        for (int nj = 0; nj < 4; ++nj) {
            int nt = (n_base >> 4) + nj;
            const uint* p = Wp + (((size_t)kt * NT_TOTAL + nt) * 64 + lane) * 8;
            uint4 w0 = *(const uint4*)p;
            uint4 w1 = *(const uint4*)(p + 4);
            uint wa[8] = {w0.x, w0.y, w0.z, w0.w, w1.x, w1.y, w1.z, w1.w};
            bf8_t bhi, blo;
#pragma unroll
            for (int j = 0; j < 8; ++j) {
                bhi[j] = (short)(wa[j] & 0xffff);
                blo[j] = (short)(wa[j] >> 16);
            }
#pragma unroll
            for (int mi = 0; mi < 4; ++mi) {
                acc[mi][nj] = __builtin_amdgcn_mfma_f32_16x16x32_bf16(ahi[mi], bhi, acc[mi][nj], 0, 0, 0);
                acc[mi][nj] = __builtin_amdgcn_mfma_f32_16x16x32_bf16(ahi[mi], blo, acc[mi][nj], 0, 0, 0);
                acc[mi][nj] = __builtin_amdgcn_mfma_f32_16x16x32_bf16(alo[mi], bhi, acc[mi][nj], 0, 0, 0);
            }
        }
    }

#pragma unroll
    for (int nj = 0; nj < 4; ++nj) {
        int col = n_base + nj * 16 + l15;
        float bv = 0.f;
        if (RELU_BIAS) bv = bias[col];
#pragma unroll
        for (int mi = 0; mi < 4; ++mi) {
#pragma unroll
            for (int r = 0; r < 4; ++r) {
                int row = m_base + mi * 16 + quad * 4 + r;
                if (row < n) {
                    float v = acc[mi][nj][r] + bv;
                    if (RELU_BIAS) v = fmaxf(v, 0.f);
                    if (OUT_SPLIT)
                        ((uint*)Cout)[(size_t)row * N + col] = pack_split(v);
                    else
                        ((ushort*)Cout)[(size_t)row * N + col] = f2bf(v);
                }
            }
        }
    }
}

extern "C" void kernel_launch(void* const* d_in, const int* in_sizes, int n_in,
                              void* d_out, int out_size, void* d_ws, size_t ws_size,
                              hipStream_t stream) {
    const float* x    = (const float*)d_in[0];
    const int*   ei_a = (const int*)d_in[1];
    const int*   ei_b = (const int*)d_in[2];
    const float* W0 = (const float*)d_in[3];
    const float* b0 = (const float*)d_in[4];
    const float* W1 = (const float*)d_in[5];
    const float* b1 = (const float*)d_in[6];
    const float* W2 = (const float*)d_in[7];
    const float* b2 = (const float*)d_in[8];
    const float* W3 = (const float*)d_in[9];
    const float* b3 = (const float*)d_in[10];
    float* out = (float*)d_out;

    const int n = in_sizes[0] / 128;  // 50000
    const int e = in_sizes[1] / 2;    // 800000

    // workspace layout
    float* ws     = (float*)d_ws;
    float* dinv_a = ws;                                   // 2n f32
    uint*  t128p  = (uint*)(ws + 2 * (size_t)n);          // n*128 uint (aliased t128b bf16)
    uint*  t256p  = t128p + 128 * (size_t)n;              // n*256 uint
    uint*  xbu    = t256p + 256 * (size_t)n;              // n*64 uint (bf16 pairs)
    uint*  Wp0    = xbu + 64 * (size_t)n;                 // 32768 each
    uint*  Wp1    = Wp0 + 32768;
    uint*  Wp2    = Wp1 + 32768;
    uint*  Wp3    = Wp2 + 32768;
    int*   iw     = (int*)(Wp3 + 32768);
    int*   cnt_a  = iw;                                   // 2n
    int*   off_a  = iw + 2 * n;                           // n+1
    int*   off_b  = off_a + (n + 1);                      // n+1
    int*   part   = off_b + (n + 1);                      // 256
    int2*  ent_a  = (int2*)(part + 256);                  // e
    int2*  ent_b  = ent_a + e;                            // e
    ushort* t128b = (ushort*)t128p;

    const int B = 256;

    // --- CSR build ---
    hipMemsetAsync(cnt_a, 0, 2 * n * sizeof(int), stream);
    k_hist<<<(e + B - 1) / B, B, 0, stream>>>(ei_a + e, ei_b + e, cnt_a, cnt_a + n, e);
    k_dinv<<<(2 * n + B - 1) / B, B, 0, stream>>>(cnt_a, dinv_a, 2 * n);

    k_scan1<<<256, 256, 0, stream>>>(cnt_a, off_a, part, n);
    k_scan2<<<1, 256, 0, stream>>>(part);
    k_scan3<<<256, 256, 0, stream>>>(off_a, part, n, e);
    k_scan1<<<256, 256, 0, stream>>>(cnt_a + n, off_b, part, n);
    k_scan2<<<1, 256, 0, stream>>>(part);
    k_scan3<<<256, 256, 0, stream>>>(off_b, part, n, e);

    hipMemsetAsync(cnt_a, 0, 2 * n * sizeof(int), stream);
    k_fill_csr<<<(e + B - 1) / B, B, 0, stream>>>(ei_a, ei_a + e, off_a, cnt_a, dinv_a, ent_a, e);
    k_fill_csr<<<(e + B - 1) / B, B, 0, stream>>>(ei_b, ei_b + e, off_b, cnt_a + n, dinv_a + n, ent_b, e);

    // --- conversions ---
    k_cvt_xb<<<(n * 64 + B - 1) / B, B, 0, stream>>>((const float2*)x, xbu, n * 64);
    k_pack_w<<<(128 * 256 + B - 1) / B, B, 0, stream>>>(W0, Wp0, 128, 256);
    k_pack_w<<<(128 * 256 + B - 1) / B, B, 0, stream>>>(W1, Wp1, 128, 256);
    k_pack_w<<<(256 * 128 + B - 1) / B, B, 0, stream>>>(W2, Wp2, 256, 128);
    k_pack_w<<<(256 * 128 + B - 1) / B, B, 0, stream>>>(W3, Wp3, 256, 128);

    // out = b2 + b3
    k_out_bias<<<(n * 128 + B - 1) / B, B, 0, stream>>>(b2, b3, out, n * 128);

    const int gather_grid = (n + 3) / 4;
    const int mblocks = (n + 127) / 128;
    for (int br = 0; br < 2; ++br) {
        const int*   off  = br == 0 ? off_a : off_b;
        const int2*  ent  = br == 0 ? ent_a : ent_b;
        const float* dinv = br == 0 ? dinv_a : dinv_a + n;
        const uint*  Wl1  = br == 0 ? Wp0 : Wp1;
        const float* bl1  = br == 0 ? b0 : b1;
        const uint*  Wl2  = br == 0 ? Wp2 : Wp3;

        // t128p = split(A_norm(x))
        k_gather_l1<<<gather_grid, B, 0, stream>>>(xbu, off, ent, dinv, t128p, n);
        // t256p = split(relu(t128 @ W[128,256] + b))
        k_gemm_mfma<128, 16, true, true><<<dim3(2, mblocks), B, 0, stream>>>(
            t128p, Wl1, bl1, (void*)t256p, n);
        // t128b = bf16(t256 @ W[256,128])
        k_gemm_mfma<256, 8, false, false><<<dim3(1, mblocks), B, 0, stream>>>(
            t256p, Wl2, nullptr, (void*)t128b, n);
        // out += A_norm(t128b)
        k_gather_l2<<<gather_grid, B, 0, stream>>>((const uint*)t128b, off, ent, dinv, out, n);
    }
}

// Round 4
// 517.462 us; speedup vs baseline: 11.0770x; 1.2283x over previous
//
#include <hip/hip_runtime.h>

// GCN ensemble: ELL (atomic-bump) adjacency + dinv-prescaled bf16 gathers + split-bf16 MFMA GEMMs.
//   agg[d] = dinv_d * (sum_s g[s] + g[d]),  g = dinv * h   (dinv folded out of edges)
//   branch: gather1(xb_scaled) -> t128 split -> gemm1 MFMA -> t256 split -> gemm2 MFMA
//           (epilogue scales by dinv, writes bf16 g) -> gather2 accumulates fp32 into out.
// Atomics write through 64B lines to HBM (measured 821 GB/s, 50MB for 400KB counters) ->
// minimize atomic COUNT: single fill does 1.6M total (was 3.2M across hist+2 fills).

typedef unsigned int uint;
typedef unsigned short ushort;
typedef __attribute__((ext_vector_type(8))) short bf8_t;
typedef __attribute__((ext_vector_type(4))) float f4_t;

#define CAP 64    // ELL slots/node; deg ~ Poisson(16), P(deg>64) < 1e-18
#define CPAD 16   // counter stride (ints)

__device__ inline ushort f2bf(float f) {
    uint u = __float_as_uint(f);
    return (ushort)((u + 0x7fff + ((u >> 16) & 1)) >> 16);
}
__device__ inline float bf2f(ushort h) { return __uint_as_float(((uint)h) << 16); }
__device__ inline uint pack_split(float f) {
    ushort hi = f2bf(f);
    ushort lo = f2bf(f - bf2f(hi));
    return (uint)hi | ((uint)lo << 16);
}

// ---------- ELL build: one kernel, both lists ----------
__global__ void k_fill_ell(const int* __restrict__ ei_a, const int* __restrict__ ei_b,
                           int* __restrict__ cntp, int* __restrict__ ell_a,
                           int* __restrict__ ell_b, int n, int e) {
    int i = blockIdx.x * blockDim.x + threadIdx.x;
    if (i >= 2 * e) return;
    int lst = i >= e;                       // blocks are list-pure (e % 256 == 0)
    int j = lst ? i - e : i;
    const int* ei = lst ? ei_b : ei_a;
    int s = ei[j], d = ei[j + e];
    int* cnt = cntp + (size_t)(lst ? n : 0) * CPAD;
    int* ell = lst ? ell_b : ell_a;
    int pos = atomicAdd(cnt + (size_t)d * CPAD, 1);
    if (pos < CAP) ell[(size_t)d * CAP + pos] = s;
}

__global__ void k_dinv(const int* __restrict__ cntp, float* __restrict__ dinv, int n2) {
    int i = blockIdx.x * blockDim.x + threadIdx.x;
    if (i < n2) dinv[i] = rsqrtf((float)cntp[(size_t)i * CPAD] + 1.0f);
}

// x fp32 -> per-branch dinv-scaled bf16 pairs (g = dinv*x)
__global__ void k_cvt(const float2* __restrict__ x2, const float* __restrict__ dinv_a,
                      const float* __restrict__ dinv_b, uint* __restrict__ xba,
                      uint* __restrict__ xbb, int n64) {
    int i = blockIdx.x * blockDim.x + threadIdx.x;
    if (i >= n64) return;
    float2 v = x2[i];
    int node = i >> 6;
    float da = dinv_a[node], db = dinv_b[node];
    xba[i] = (uint)f2bf(da * v.x) | ((uint)f2bf(da * v.y) << 16);
    xbb[i] = (uint)f2bf(db * v.x) | ((uint)f2bf(db * v.y) << 16);
}

// all 4 weights -> MFMA-frag split-bf16 packing, one kernel
// Wp[seg*32768 + (((kt*NT+nt)*64 + quad*16+(n&15))*8 + k&7] = pack_split(W[k][n])
__global__ void k_pack_all(const float* __restrict__ W0, const float* __restrict__ W1,
                           const float* __restrict__ W2, const float* __restrict__ W3,
                           uint* __restrict__ Wp) {
    int i = blockIdx.x * blockDim.x + threadIdx.x;
    if (i >= 4 * 32768) return;
    int seg = i >> 15;
    int r = i & 32767;
    const float* W = seg == 0 ? W0 : seg == 1 ? W1 : seg == 2 ? W2 : W3;
    int N = seg < 2 ? 256 : 128;
    int k = r / N, nn = r - k * N;
    int kt = k >> 5, q = (k & 31) >> 3, jj = k & 7;
    int nt = nn >> 4, ln = q * 16 + (nn & 15);
    int NT = N >> 4;
    Wp[(size_t)seg * 32768 + (((size_t)(kt * NT + nt)) * 64 + ln) * 8 + jj] = pack_split(W[r]);
}

// ---------- gathers: one wave/node, lane = 2 feats, 4-deep index batching ----------

__global__ __launch_bounds__(256) void k_gather_l1(
    const uint* __restrict__ xb, const int* __restrict__ cntp, const int* __restrict__ ell,
    const float* __restrict__ dinv, uint* __restrict__ t128p, int n) {
    int node = (blockIdx.x * 256 + threadIdx.x) >> 6;
    if (node >= n) return;
    node = __builtin_amdgcn_readfirstlane(node);
    const int lane = threadIdx.x & 63;
    int m = cntp[(size_t)node * CPAD];
    m = m < CAP ? m : CAP;
    const int* ep = ell + (size_t)node * CAP;
    float ax = 0.f, ay = 0.f;
    int j = 0;
    for (; j + 4 <= m; j += 4) {
        int4 s4 = *(const int4*)(ep + j);
        uint u0 = xb[(size_t)s4.x * 64 + lane];
        uint u1 = xb[(size_t)s4.y * 64 + lane];
        uint u2 = xb[(size_t)s4.z * 64 + lane];
        uint u3 = xb[(size_t)s4.w * 64 + lane];
        ax += bf2f((ushort)u0) + bf2f((ushort)u1) + bf2f((ushort)u2) + bf2f((ushort)u3);
        ay += bf2f((ushort)(u0 >> 16)) + bf2f((ushort)(u1 >> 16)) +
              bf2f((ushort)(u2 >> 16)) + bf2f((ushort)(u3 >> 16));
    }
    for (; j < m; ++j) {
        uint u = xb[(size_t)ep[j] * 64 + lane];
        ax += bf2f((ushort)u);
        ay += bf2f((ushort)(u >> 16));
    }
    uint us = xb[(size_t)node * 64 + lane];
    float di = dinv[node];
    uint2 o;
    o.x = pack_split(di * (ax + bf2f((ushort)us)));
    o.y = pack_split(di * (ay + bf2f((ushort)(us >> 16))));
    *(uint2*)(t128p + (size_t)node * 128 + lane * 2) = o;
}

// INIT=1: out = (b2+b3) + v (branch 0);  INIT=0: out += v (branch 1)
template <int INIT>
__global__ __launch_bounds__(256) void k_gather_l2(
    const uint* __restrict__ hb, const int* __restrict__ cntp, const int* __restrict__ ell,
    const float* __restrict__ dinv, const float* __restrict__ b2, const float* __restrict__ b3,
    float* __restrict__ out, int n) {
    int node = (blockIdx.x * 256 + threadIdx.x) >> 6;
    if (node >= n) return;
    node = __builtin_amdgcn_readfirstlane(node);
    const int lane = threadIdx.x & 63;
    int m = cntp[(size_t)node * CPAD];
    m = m < CAP ? m : CAP;
    const int* ep = ell + (size_t)node * CAP;
    float ax = 0.f, ay = 0.f;
    int j = 0;
    for (; j + 4 <= m; j += 4) {
        int4 s4 = *(const int4*)(ep + j);
        uint u0 = hb[(size_t)s4.x * 64 + lane];
        uint u1 = hb[(size_t)s4.y * 64 + lane];
        uint u2 = hb[(size_t)s4.z * 64 + lane];
        uint u3 = hb[(size_t)s4.w * 64 + lane];
        ax += bf2f((ushort)u0) + bf2f((ushort)u1) + bf2f((ushort)u2) + bf2f((ushort)u3);
        ay += bf2f((ushort)(u0 >> 16)) + bf2f((ushort)(u1 >> 16)) +
              bf2f((ushort)(u2 >> 16)) + bf2f((ushort)(u3 >> 16));
    }
    for (; j < m; ++j) {
        uint u = hb[(size_t)ep[j] * 64 + lane];
        ax += bf2f((ushort)u);
        ay += bf2f((ushort)(u >> 16));
    }
    uint us = hb[(size_t)node * 64 + lane];
    float di = dinv[node];
    float vx = di * (ax + bf2f((ushort)us));
    float vy = di * (ay + bf2f((ushort)(us >> 16)));
    const int f = lane * 2;
    float2* op = (float2*)(out + (size_t)node * 128 + f);
    float2 cur;
    if (INIT) {
        cur.x = b2[f] + b3[f];
        cur.y = b2[f + 1] + b3[f + 1];
    } else {
        cur = *op;
    }
    cur.x += vx;
    cur.y += vy;
    *op = cur;
}

// ---------- MFMA GEMM (split-bf16, 3 MFMA/term) ----------
// MODE 0: +bias, relu, write packed split uint. MODE 1: scale by aux[row], write bf16.
template <int K, int NT_TOTAL, int MODE>
__global__ __launch_bounds__(256) void k_gemm_mfma(
    const uint* __restrict__ Ap, const uint* __restrict__ Wp,
    const float* __restrict__ aux, void* __restrict__ Cout, int n) {
    const int lane = threadIdx.x & 63;
    const int wave = threadIdx.x >> 6;
    const int l15 = lane & 15;
    const int quad = lane >> 4;
    const int m_base = blockIdx.y * 128 + (wave >> 1) * 64;
    const int n_base = blockIdx.x * 128 + (wave & 1) * 64;
    const int N = NT_TOTAL * 16;

    f4_t acc[4][4];
#pragma unroll
    for (int a = 0; a < 4; ++a)
#pragma unroll
        for (int b = 0; b < 4; ++b) acc[a][b] = (f4_t){0.f, 0.f, 0.f, 0.f};

#pragma unroll
    for (int kt = 0; kt < K / 32; ++kt) {
        bf8_t ahi[4], alo[4];
#pragma unroll
        for (int mi = 0; mi < 4; ++mi) {
            int row = m_base + mi * 16 + l15;
            uint4 u0 = {0, 0, 0, 0}, u1 = {0, 0, 0, 0};
            if (row < n) {
                const uint* p = Ap + (size_t)row * K + kt * 32 + quad * 8;
                u0 = *(const uint4*)p;
                u1 = *(const uint4*)(p + 4);
            }
            uint ua[8] = {u0.x, u0.y, u0.z, u0.w, u1.x, u1.y, u1.z, u1.w};
#pragma unroll
            for (int j = 0; j < 8; ++j) {
                ahi[mi][j] = (short)(ua[j] & 0xffff);
                alo[mi][j] = (short)(ua[j] >> 16);
            }
        }
#pragma unroll
        for (int nj = 0; nj < 4; ++nj) {
            int nt = (n_base >> 4) + nj;
            const uint* p = Wp + (((size_t)kt * NT_TOTAL + nt) * 64 + lane) * 8;
            uint4 w0 = *(const uint4*)p;
            uint4 w1 = *(const uint4*)(p + 4);
            uint wa[8] = {w0.x, w0.y, w0.z, w0.w, w1.x, w1.y, w1.z, w1.w};
            bf8_t bhi, blo;
#pragma unroll
            for (int j = 0; j < 8; ++j) {
                bhi[j] = (short)(wa[j] & 0xffff);
                blo[j] = (short)(wa[j] >> 16);
            }
#pragma unroll
            for (int mi = 0; mi < 4; ++mi) {
                acc[mi][nj] = __builtin_amdgcn_mfma_f32_16x16x32_bf16(ahi[mi], bhi, acc[mi][nj], 0, 0, 0);
                acc[mi][nj] = __builtin_amdgcn_mfma_f32_16x16x32_bf16(ahi[mi], blo, acc[mi][nj], 0, 0, 0);
                acc[mi][nj] = __builtin_amdgcn_mfma_f32_16x16x32_bf16(alo[mi], bhi, acc[mi][nj], 0, 0, 0);
            }
        }
    }

#pragma unroll
    for (int nj = 0; nj < 4; ++nj) {
        int col = n_base + nj * 16 + l15;
        float bv = 0.f;
        if (MODE == 0) bv = aux[col];
#pragma unroll
        for (int mi = 0; mi < 4; ++mi) {
#pragma unroll
            for (int r = 0; r < 4; ++r) {
                int row = m_base + mi * 16 + quad * 4 + r;
                if (row < n) {
                    float v = acc[mi][nj][r];
                    if (MODE == 0) {
                        v = fmaxf(v + bv, 0.f);
                        ((uint*)Cout)[(size_t)row * N + col] = pack_split(v);
                    } else {
                        v *= aux[row];  // dinv scaling: write g = dinv*h
                        ((ushort*)Cout)[(size_t)row * N + col] = f2bf(v);
                    }
                }
            }
        }
    }
}

extern "C" void kernel_launch(void* const* d_in, const int* in_sizes, int n_in,
                              void* d_out, int out_size, void* d_ws, size_t ws_size,
                              hipStream_t stream) {
    const float* x    = (const float*)d_in[0];
    const int*   ei_a = (const int*)d_in[1];
    const int*   ei_b = (const int*)d_in[2];
    const float* W0 = (const float*)d_in[3];
    const float* b0 = (const float*)d_in[4];
    const float* W1 = (const float*)d_in[5];
    const float* b1 = (const float*)d_in[6];
    const float* W2 = (const float*)d_in[7];
    const float* b2 = (const float*)d_in[8];
    const float* W3 = (const float*)d_in[9];
    const float* b3 = (const float*)d_in[10];
    float* out = (float*)d_out;

    const int n = in_sizes[0] / 128;  // 50000
    const int e = in_sizes[1] / 2;    // 800000

    // workspace
    float* ws     = (float*)d_ws;
    float* dinv_a = ws;                                 // 2n (a|b)
    uint*  t128p  = (uint*)(ws + 2 * (size_t)n);        // 128n
    uint*  t256p  = t128p + 128 * (size_t)n;            // 256n
    uint*  xba    = t256p + 256 * (size_t)n;            // 64n
    uint*  xbb    = xba + 64 * (size_t)n;               // 64n
    uint*  Wp     = xbb + 64 * (size_t)n;               // 4*32768
    int*   cntp   = (int*)(Wp + 4 * 32768);             // 2n*CPAD
    int*   ell_a  = cntp + 2 * (size_t)n * CPAD;        // n*CAP
    int*   ell_b  = ell_a + (size_t)n * CAP;            // n*CAP
    ushort* t128b = (ushort*)t128p;

    const int B = 256;

    hipMemsetAsync(cntp, 0, 2 * (size_t)n * CPAD * sizeof(int), stream);
    k_fill_ell<<<(2 * e + B - 1) / B, B, 0, stream>>>(ei_a, ei_b, cntp, ell_a, ell_b, n, e);
    k_dinv<<<(2 * n + B - 1) / B, B, 0, stream>>>(cntp, dinv_a, 2 * n);
    k_cvt<<<(n * 64 + B - 1) / B, B, 0, stream>>>((const float2*)x, dinv_a, dinv_a + n,
                                                  xba, xbb, n * 64);
    k_pack_all<<<(4 * 32768 + B - 1) / B, B, 0, stream>>>(W0, W1, W2, W3, Wp);

    const int gather_grid = (n + 3) / 4;
    const int mblocks = (n + 127) / 128;

    // branch 0
    k_gather_l1<<<gather_grid, B, 0, stream>>>(xba, cntp, ell_a, dinv_a, t128p, n);
    k_gemm_mfma<128, 16, 0><<<dim3(2, mblocks), B, 0, stream>>>(t128p, Wp, b0, (void*)t256p, n);
    k_gemm_mfma<256, 8, 1><<<dim3(1, mblocks), B, 0, stream>>>(t256p, Wp + 2 * 32768, dinv_a,
                                                               (void*)t128b, n);
    k_gather_l2<1><<<gather_grid, B, 0, stream>>>((const uint*)t128b, cntp, ell_a, dinv_a,
                                                  b2, b3, out, n);
    // branch 1
    k_gather_l1<<<gather_grid, B, 0, stream>>>(xbb, cntp + (size_t)n * CPAD, ell_b,
                                               dinv_a + n, t128p, n);
    k_gemm_mfma<128, 16, 0><<<dim3(2, mblocks), B, 0, stream>>>(t128p, Wp + 32768, b1,
                                                                (void*)t256p, n);
    k_gemm_mfma<256, 8, 1><<<dim3(1, mblocks), B, 0, stream>>>(t256p, Wp + 3 * 32768,
                                                               dinv_a + n, (void*)t128b, n);
    k_gather_l2<0><<<gather_grid, B, 0, stream>>>((const uint*)t128b, cntp + (size_t)n * CPAD,
                                                  ell_b, dinv_a + n, nullptr, nullptr, out, n);
}

// Round 5
// 512.284 us; speedup vs baseline: 11.1890x; 1.0101x over previous
//
#include <hip/hip_runtime.h>

// GCN ensemble: ELL (atomic-bump, DENSE counters) + dinv-prescaled bf16 gathers +
// split-bf16 MFMA GEMMs. Counters dense: atomics to the same 64B line merge in TCC
// (measured: dense hist = 31 B/atomic vs padded fill = 54 B/atomic write-through).
//   agg[d] = dinv_d * (sum_s g[s] + g[d]),  g = dinv * h
//   pipeline: fill_ell -> cvt(+dinv) -> pack -> gather1(both) ->
//             [gemm1,gemm2] x2 -> gather2(both branches + bias, single out pass)

typedef unsigned int uint;
typedef unsigned short ushort;
typedef __attribute__((ext_vector_type(8))) short bf8_t;
typedef __attribute__((ext_vector_type(4))) float f4_t;

#define CAP 64  // ELL slots/node; deg ~ Poisson(16), P(overflow) negligible

__device__ inline ushort f2bf(float f) {
    uint u = __float_as_uint(f);
    return (ushort)((u + 0x7fff + ((u >> 16) & 1)) >> 16);
}
__device__ inline float bf2f(ushort h) { return __uint_as_float(((uint)h) << 16); }
__device__ inline uint pack_split(float f) {
    ushort hi = f2bf(f);
    ushort lo = f2bf(f - bf2f(hi));
    return (uint)hi | ((uint)lo << 16);
}

// ---------- ELL build: one kernel, both lists, dense counters ----------
__global__ void k_fill_ell(const int* __restrict__ ei_a, const int* __restrict__ ei_b,
                           int* __restrict__ cnt, int* __restrict__ ell_a,
                           int* __restrict__ ell_b, int n, int e) {
    int i = blockIdx.x * blockDim.x + threadIdx.x;
    if (i >= 2 * e) return;
    int lst = i >= e;  // blocks are list-pure (e % 256 == 0)
    int j = lst ? i - e : i;
    const int* ei = lst ? ei_b : ei_a;
    int s = ei[j], d = ei[j + e];
    int* c = cnt + (lst ? n : 0);
    int* ell = lst ? ell_b : ell_a;
    int pos = atomicAdd(c + d, 1);
    if (pos < CAP) ell[(size_t)d * CAP + pos] = s;
}

// x fp32 -> per-branch dinv-scaled bf16 pairs (g = dinv*x); lane0 also stores dinv.
__global__ void k_cvt_dinv(const float2* __restrict__ x2, const int* __restrict__ cnt,
                           float* __restrict__ dinv, uint* __restrict__ xba,
                           uint* __restrict__ xbb, int n) {
    int i = blockIdx.x * blockDim.x + threadIdx.x;
    if (i >= n * 64) return;
    int node = i >> 6;
    float da = rsqrtf((float)cnt[node] + 1.0f);
    float db = rsqrtf((float)cnt[n + node] + 1.0f);
    if ((i & 63) == 0) {
        dinv[node] = da;
        dinv[n + node] = db;
    }
    float2 v = x2[i];
    xba[i] = (uint)f2bf(da * v.x) | ((uint)f2bf(da * v.y) << 16);
    xbb[i] = (uint)f2bf(db * v.x) | ((uint)f2bf(db * v.y) << 16);
}

// all 4 weights -> MFMA-frag split-bf16 packing, one kernel
__global__ void k_pack_all(const float* __restrict__ W0, const float* __restrict__ W1,
                           const float* __restrict__ W2, const float* __restrict__ W3,
                           uint* __restrict__ Wp) {
    int i = blockIdx.x * blockDim.x + threadIdx.x;
    if (i >= 4 * 32768) return;
    int seg = i >> 15;
    int r = i & 32767;
    const float* W = seg == 0 ? W0 : seg == 1 ? W1 : seg == 2 ? W2 : W3;
    int N = seg < 2 ? 256 : 128;
    int k = r / N, nn = r - k * N;
    int kt = k >> 5, q = (k & 31) >> 3, jj = k & 7;
    int nt = nn >> 4, ln = q * 16 + (nn & 15);
    int NT = N >> 4;
    Wp[(size_t)seg * 32768 + (((size_t)(kt * NT + nt)) * 64 + ln) * 8 + jj] = pack_split(W[r]);
}

// ---------- gather helpers: one wave/node, lane = 2 feats, 4-deep batching ----------
__device__ inline void gather_row(const uint* __restrict__ xb, const int* __restrict__ ep,
                                  int m, int lane, float& ax, float& ay) {
    int j = 0;
    for (; j + 4 <= m; j += 4) {
        int4 s4 = *(const int4*)(ep + j);
        uint u0 = xb[(size_t)s4.x * 64 + lane];
        uint u1 = xb[(size_t)s4.y * 64 + lane];
        uint u2 = xb[(size_t)s4.z * 64 + lane];
        uint u3 = xb[(size_t)s4.w * 64 + lane];
        ax += bf2f((ushort)u0) + bf2f((ushort)u1) + bf2f((ushort)u2) + bf2f((ushort)u3);
        ay += bf2f((ushort)(u0 >> 16)) + bf2f((ushort)(u1 >> 16)) +
              bf2f((ushort)(u2 >> 16)) + bf2f((ushort)(u3 >> 16));
    }
    for (; j < m; ++j) {
        uint u = xb[(size_t)ep[j] * 64 + lane];
        ax += bf2f((ushort)u);
        ay += bf2f((ushort)(u >> 16));
    }
}

// layer1, both branches in one launch: blocks [0,gb) = branch a, [gb,2gb) = branch b
__global__ __launch_bounds__(256) void k_gather_l1(
    const uint* __restrict__ xba, const uint* __restrict__ xbb, const int* __restrict__ cnt,
    const int* __restrict__ ell_a, const int* __restrict__ ell_b,
    const float* __restrict__ dinv, uint* __restrict__ ta, uint* __restrict__ tb,
    int n, int gb) {
    int bid = blockIdx.x;
    int br = bid >= gb;
    const uint* xb = br ? xbb : xba;
    const int* ell = br ? ell_b : ell_a;
    const int* c = cnt + (br ? n : 0);
    const float* dv = dinv + (br ? n : 0);
    uint* outp = br ? tb : ta;
    int node = ((bid - (br ? gb : 0)) * 256 + (int)threadIdx.x) >> 6;
    if (node >= n) return;
    node = __builtin_amdgcn_readfirstlane(node);
    const int lane = threadIdx.x & 63;
    int m = c[node];
    m = m < CAP ? m : CAP;
    float ax = 0.f, ay = 0.f;
    gather_row(xb, ell + (size_t)node * CAP, m, lane, ax, ay);
    uint us = xb[(size_t)node * 64 + lane];
    float di = dv[node];
    uint2 o;
    o.x = pack_split(di * (ax + bf2f((ushort)us)));
    o.y = pack_split(di * (ay + bf2f((ushort)(us >> 16))));
    *(uint2*)(outp + (size_t)node * 128 + lane * 2) = o;
}

// layer2, BOTH branches + bias in one kernel; single write pass over out.
__global__ __launch_bounds__(256) void k_gather_l2(
    const uint* __restrict__ hba, const uint* __restrict__ hbb, const int* __restrict__ cnt,
    const int* __restrict__ ell_a, const int* __restrict__ ell_b,
    const float* __restrict__ dinv, const float* __restrict__ b2,
    const float* __restrict__ b3, float* __restrict__ out, int n) {
    int node = (blockIdx.x * 256 + (int)threadIdx.x) >> 6;
    if (node >= n) return;
    node = __builtin_amdgcn_readfirstlane(node);
    const int lane = threadIdx.x & 63;

    // branch a
    int ma = cnt[node];
    ma = ma < CAP ? ma : CAP;
    float ax = 0.f, ay = 0.f;
    gather_row(hba, ell_a + (size_t)node * CAP, ma, lane, ax, ay);
    uint usa = hba[(size_t)node * 64 + lane];
    float da = dinv[node];
    float vx = da * (ax + bf2f((ushort)usa));
    float vy = da * (ay + bf2f((ushort)(usa >> 16)));

    // branch b
    int mb = cnt[n + node];
    mb = mb < CAP ? mb : CAP;
    float bx = 0.f, by = 0.f;
    gather_row(hbb, ell_b + (size_t)node * CAP, mb, lane, bx, by);
    uint usb = hbb[(size_t)node * 64 + lane];
    float db = dinv[n + node];
    vx += db * (bx + bf2f((ushort)usb));
    vy += db * (by + bf2f((ushort)(usb >> 16)));

    const int f = lane * 2;
    float2 o;
    o.x = b2[f] + b3[f] + vx;
    o.y = b2[f + 1] + b3[f + 1] + vy;
    *(float2*)(out + (size_t)node * 128 + f) = o;
}

// ---------- MFMA GEMM (split-bf16, 3 MFMA/term) ----------
// MODE 0: +bias, relu, write packed split uint. MODE 1: scale by aux[row], write bf16.
template <int K, int NT_TOTAL, int MODE>
__global__ __launch_bounds__(256) void k_gemm_mfma(
    const uint* __restrict__ Ap, const uint* __restrict__ Wp,
    const float* __restrict__ aux, void* __restrict__ Cout, int n) {
    const int lane = threadIdx.x & 63;
    const int wave = threadIdx.x >> 6;
    const int l15 = lane & 15;
    const int quad = lane >> 4;
    const int m_base = blockIdx.y * 128 + (wave >> 1) * 64;
    const int n_base = blockIdx.x * 128 + (wave & 1) * 64;
    const int N = NT_TOTAL * 16;

    f4_t acc[4][4];
#pragma unroll
    for (int a = 0; a < 4; ++a)
#pragma unroll
        for (int b = 0; b < 4; ++b) acc[a][b] = (f4_t){0.f, 0.f, 0.f, 0.f};

#pragma unroll
    for (int kt = 0; kt < K / 32; ++kt) {
        bf8_t ahi[4], alo[4];
#pragma unroll
        for (int mi = 0; mi < 4; ++mi) {
            int row = m_base + mi * 16 + l15;
            uint4 u0 = {0, 0, 0, 0}, u1 = {0, 0, 0, 0};
            if (row < n) {
                const uint* p = Ap + (size_t)row * K + kt * 32 + quad * 8;
                u0 = *(const uint4*)p;
                u1 = *(const uint4*)(p + 4);
            }
            uint ua[8] = {u0.x, u0.y, u0.z, u0.w, u1.x, u1.y, u1.z, u1.w};
#pragma unroll
            for (int j = 0; j < 8; ++j) {
                ahi[mi][j] = (short)(ua[j] & 0xffff);
                alo[mi][j] = (short)(ua[j] >> 16);
            }
        }
#pragma unroll
        for (int nj = 0; nj < 4; ++nj) {
            int nt = (n_base >> 4) + nj;
            const uint* p = Wp + (((size_t)kt * NT_TOTAL + nt) * 64 + lane) * 8;
            uint4 w0 = *(const uint4*)p;
            uint4 w1 = *(const uint4*)(p + 4);
            uint wa[8] = {w0.x, w0.y, w0.z, w0.w, w1.x, w1.y, w1.z, w1.w};
            bf8_t bhi, blo;
#pragma unroll
            for (int j = 0; j < 8; ++j) {
                bhi[j] = (short)(wa[j] & 0xffff);
                blo[j] = (short)(wa[j] >> 16);
            }
#pragma unroll
            for (int mi = 0; mi < 4; ++mi) {
                acc[mi][nj] = __builtin_amdgcn_mfma_f32_16x16x32_bf16(ahi[mi], bhi, acc[mi][nj], 0, 0, 0);
                acc[mi][nj] = __builtin_amdgcn_mfma_f32_16x16x32_bf16(ahi[mi], blo, acc[mi][nj], 0, 0, 0);
                acc[mi][nj] = __builtin_amdgcn_mfma_f32_16x16x32_bf16(alo[mi], bhi, acc[mi][nj], 0, 0, 0);
            }
        }
    }

#pragma unroll
    for (int nj = 0; nj < 4; ++nj) {
        int col = n_base + nj * 16 + l15;
        float bv = 0.f;
        if (MODE == 0) bv = aux[col];
#pragma unroll
        for (int mi = 0; mi < 4; ++mi) {
#pragma unroll
            for (int r = 0; r < 4; ++r) {
                int row = m_base + mi * 16 + quad * 4 + r;
                if (row < n) {
                    float v = acc[mi][nj][r];
                    if (MODE == 0) {
                        v = fmaxf(v + bv, 0.f);
                        ((uint*)Cout)[(size_t)row * N + col] = pack_split(v);
                    } else {
                        v *= aux[row];  // write g = dinv*h
                        ((ushort*)Cout)[(size_t)row * N + col] = f2bf(v);
                    }
                }
            }
        }
    }
}

extern "C" void kernel_launch(void* const* d_in, const int* in_sizes, int n_in,
                              void* d_out, int out_size, void* d_ws, size_t ws_size,
                              hipStream_t stream) {
    const float* x    = (const float*)d_in[0];
    const int*   ei_a = (const int*)d_in[1];
    const int*   ei_b = (const int*)d_in[2];
    const float* W0 = (const float*)d_in[3];
    const float* b0 = (const float*)d_in[4];
    const float* W1 = (const float*)d_in[5];
    const float* b1 = (const float*)d_in[6];
    const float* W2 = (const float*)d_in[7];
    const float* b2 = (const float*)d_in[8];
    const float* W3 = (const float*)d_in[9];
    const float* b3 = (const float*)d_in[10];
    float* out = (float*)d_out;

    const int n = in_sizes[0] / 128;  // 50000
    const int e = in_sizes[1] / 2;    // 800000

    // workspace (~155 MB)
    float* ws     = (float*)d_ws;
    float* dinv   = ws;                               // 2n (a|b)
    uint*  ta     = (uint*)(ws + 2 * (size_t)n);      // 128n  (t128p_a; aliased t128b_a)
    uint*  tb     = ta + 128 * (size_t)n;             // 128n  (t128p_b; aliased t128b_b)
    uint*  t256p  = tb + 128 * (size_t)n;             // 256n
    uint*  xba    = t256p + 256 * (size_t)n;          // 64n
    uint*  xbb    = xba + 64 * (size_t)n;             // 64n
    uint*  Wp     = xbb + 64 * (size_t)n;             // 4*32768
    int*   cnt    = (int*)(Wp + 4 * 32768);           // 2n (dense!)
    int*   ell_a  = cnt + 2 * (size_t)n;              // n*CAP
    int*   ell_b  = ell_a + (size_t)n * CAP;          // n*CAP
    ushort* tba   = (ushort*)ta;
    ushort* tbb   = (ushort*)tb;

    const int B = 256;

    hipMemsetAsync(cnt, 0, 2 * (size_t)n * sizeof(int), stream);
    k_fill_ell<<<(2 * e + B - 1) / B, B, 0, stream>>>(ei_a, ei_b, cnt, ell_a, ell_b, n, e);
    k_cvt_dinv<<<(n * 64 + B - 1) / B, B, 0, stream>>>((const float2*)x, cnt, dinv,
                                                       xba, xbb, n);
    k_pack_all<<<(4 * 32768 + B - 1) / B, B, 0, stream>>>(W0, W1, W2, W3, Wp);

    const int gb = (n + 3) / 4;  // blocks per branch (4 nodes/block)
    const int mblocks = (n + 127) / 128;

    k_gather_l1<<<2 * gb, B, 0, stream>>>(xba, xbb, cnt, ell_a, ell_b, dinv, ta, tb, n, gb);

    // branch a GEMMs
    k_gemm_mfma<128, 16, 0><<<dim3(2, mblocks), B, 0, stream>>>(ta, Wp, b0, (void*)t256p, n);
    k_gemm_mfma<256, 8, 1><<<dim3(1, mblocks), B, 0, stream>>>(t256p, Wp + 2 * 32768, dinv,
                                                               (void*)tba, n);
    // branch b GEMMs
    k_gemm_mfma<128, 16, 0><<<dim3(2, mblocks), B, 0, stream>>>(tb, Wp + 32768, b1,
                                                                (void*)t256p, n);
    k_gemm_mfma<256, 8, 1><<<dim3(1, mblocks), B, 0, stream>>>(t256p, Wp + 3 * 32768,
                                                               dinv + n, (void*)tbb, n);

    // final: out = b2+b3 + agg_a + agg_b, single pass
    k_gather_l2<<<gb, B, 0, stream>>>((const uint*)tba, (const uint*)tbb, cnt, ell_a, ell_b,
                                      dinv, b2, b3, out, n);
}

// Round 6
// 465.965 us; speedup vs baseline: 12.3012x; 1.0994x over previous
//
#include <hip/hip_runtime.h>

// GCN ensemble: atomic-free two-level counting-sort CSR build + dinv-prescaled bf16
// gathers + split-bf16 MFMA GEMMs.
// R5 lesson: scattered 4B stores + device atomics each cost ~30-60B of line-granular
// HBM/fabric traffic (fill_ell: 96MB written for 6.4MB of payload). This build does all
// counting in LDS and every global write sequential/region-confined:
//   P1: per-WG LDS hist over dst-buckets (64 nodes) -> dense cnt matrix
//   P2a: per-bucket prefix over WGs (wave shfl-scan)   P2b: bucket-offset scan (1 WG)
//   P3: re-read edges, LDS bump, write packed (dst%64)<<17|src to contiguous segments
//   P4: WG/bucket: LDS 64-node hist+scan -> node CSR offsets + dinv; scatter within 4KB
// Math: agg[d] = dinv_d * (sum_s g[s] + g[d]), g = dinv*h; dinv folded out of edges.

typedef unsigned int uint;
typedef unsigned short ushort;
typedef __attribute__((ext_vector_type(8))) short bf8_t;
typedef __attribute__((ext_vector_type(4))) float f4_t;

#define CHUNK 16384  // edges per WG in P1/P3; NW = ceil(e/CHUNK) must be <= 64
#define MAXNB 800    // max buckets (n <= 51200)

__device__ inline ushort f2bf(float f) {
    uint u = __float_as_uint(f);
    return (ushort)((u + 0x7fff + ((u >> 16) & 1)) >> 16);
}
__device__ inline float bf2f(ushort h) { return __uint_as_float(((uint)h) << 16); }
__device__ inline uint pack_split(float f) {
    ushort hi = f2bf(f);
    ushort lo = f2bf(f - bf2f(hi));
    return (uint)hi | ((uint)lo << 16);
}

// ---------- P1: per-chunk bucket histogram (LDS), dense writes ----------
__global__ __launch_bounds__(256) void k_p1_hist(
    const int* __restrict__ ei_a, const int* __restrict__ ei_b,
    int* __restrict__ cnt_mat, int e, int NB, int NW) {
    __shared__ int lh[MAXNB];
    int l = blockIdx.x / NW, w = blockIdx.x % NW;
    const int* dst = (l ? ei_b : ei_a) + e;
    for (int t = threadIdx.x; t < NB; t += 256) lh[t] = 0;
    __syncthreads();
    int beg = w * CHUNK, end = min(beg + CHUNK, e);
    for (int j = beg + threadIdx.x; j < end; j += 256) atomicAdd(&lh[dst[j] >> 6], 1);
    __syncthreads();
    int* outp = cnt_mat + ((size_t)l * NW + w) * NB;
    for (int t = threadIdx.x; t < NB; t += 256) outp[t] = lh[t];
}

// ---------- P2a: per-bucket exclusive prefix over WGs (one wave per bucket) ----------
__global__ __launch_bounds__(256) void k_p2a(const int* __restrict__ cnt_mat,
                                             int* __restrict__ wgoff, int* __restrict__ btot,
                                             int NB, int NW) {
    int which = blockIdx.x * 4 + ((int)threadIdx.x >> 6);
    if (which >= 2 * NB) return;
    int lane = threadIdx.x & 63;
    int l = which / NB, b = which - l * NB;
    int v = (lane < NW) ? cnt_mat[((size_t)l * NW + lane) * NB + b] : 0;
    int s = v;
#pragma unroll
    for (int o = 1; o < 64; o <<= 1) {
        int t = __shfl_up(s, o, 64);
        if (lane >= o) s += t;
    }
    if (lane < NW) wgoff[((size_t)l * NB + b) * 64 + lane] = s - v;
    if (lane == 63) btot[which] = s;
}

// ---------- P2b: exclusive scan of bucket totals per list (one WG) ----------
__global__ __launch_bounds__(256) void k_p2b(const int* __restrict__ btot,
                                             int* __restrict__ boff, int NB, int e) {
    __shared__ int s[1024];
    for (int l = 0; l < 2; ++l) {
        for (int t = threadIdx.x; t < 1024; t += 256) s[t] = (t < NB) ? btot[l * NB + t] : 0;
        __syncthreads();
        for (int o = 1; o < 1024; o <<= 1) {
            int tmp[4];
#pragma unroll
            for (int k = 0; k < 4; ++k) {
                int idx = threadIdx.x + k * 256;
                tmp[k] = (idx >= o) ? s[idx - o] : 0;
            }
            __syncthreads();
#pragma unroll
            for (int k = 0; k < 4; ++k) s[threadIdx.x + k * 256] += tmp[k];
            __syncthreads();
        }
        for (int t = threadIdx.x; t < NB; t += 256)
            boff[l * (NB + 1) + t] = s[t] - btot[l * NB + t];
        if (threadIdx.x == 0) boff[l * (NB + 1) + NB] = e;
        __syncthreads();
    }
}

// ---------- P3: scatter packed entries into contiguous per-(WG,bucket) segments ----------
__global__ __launch_bounds__(256) void k_p3_scatter(
    const int* __restrict__ ei_a, const int* __restrict__ ei_b,
    const int* __restrict__ wgoff, const int* __restrict__ boff,
    int* __restrict__ ebuf_a, int* __restrict__ ebuf_b, int e, int NB, int NW) {
    __shared__ int base[MAXNB];
    __shared__ int bump[MAXNB];
    int l = blockIdx.x / NW, w = blockIdx.x % NW;
    const int* ei = l ? ei_b : ei_a;
    int* ebuf = l ? ebuf_b : ebuf_a;
    for (int t = threadIdx.x; t < NB; t += 256) {
        base[t] = boff[l * (NB + 1) + t] + wgoff[((size_t)l * NB + t) * 64 + w];
        bump[t] = 0;
    }
    __syncthreads();
    int beg = w * CHUNK, end = min(beg + CHUNK, e);
    for (int j = beg + threadIdx.x; j < end; j += 256) {
        int sv = ei[j], d = ei[e + j];
        int b = d >> 6;
        int pos = base[b] + atomicAdd(&bump[b], 1);
        ebuf[pos] = ((d & 63) << 17) | sv;
    }
}

// ---------- P4: within-bucket node sort -> final CSR + noff + dinv ----------
__global__ __launch_bounds__(256) void k_p4_nodesort(
    const int* __restrict__ ebuf_a, const int* __restrict__ ebuf_b,
    const int* __restrict__ boff, int* __restrict__ csr_a, int* __restrict__ csr_b,
    int* __restrict__ noff, float* __restrict__ dinv, int n, int e, int NB) {
    __shared__ int hist[64], nstart[64];
    int which = blockIdx.x;
    int l = which / NB, b = which - l * NB;
    const int* ebuf = l ? ebuf_b : ebuf_a;
    int* csr = l ? csr_b : csr_a;
    int seg0 = boff[l * (NB + 1) + b], seg1 = boff[l * (NB + 1) + b + 1];
    if (threadIdx.x < 64) hist[threadIdx.x] = 0;
    __syncthreads();
    for (int j = seg0 + (int)threadIdx.x; j < seg1; j += 256)
        atomicAdd(&hist[ebuf[j] >> 17], 1);
    __syncthreads();
    if (threadIdx.x < 64) {
        int v = hist[threadIdx.x];
        int s = v;
#pragma unroll
        for (int o = 1; o < 64; o <<= 1) {
            int t = __shfl_up(s, o, 64);
            if ((int)threadIdx.x >= o) s += t;
        }
        int node = b * 64 + (int)threadIdx.x;
        nstart[threadIdx.x] = seg0 + s - v;
        if (node < n) {
            noff[(size_t)l * (n + 1) + node] = seg0 + s - v;
            dinv[(size_t)l * n + node] = rsqrtf((float)v + 1.0f);
        }
        hist[threadIdx.x] = 0;  // reuse as bump counter
    }
    if (b == NB - 1 && threadIdx.x == 0) noff[(size_t)l * (n + 1) + n] = e;
    __syncthreads();
    for (int j = seg0 + (int)threadIdx.x; j < seg1; j += 256) {
        int pk = ebuf[j];
        int ni = pk >> 17;
        int pos = nstart[ni] + atomicAdd(&hist[ni], 1);
        csr[pos] = pk & 0x1ffff;
    }
}

// ---------- conversions ----------
// x fp32 -> per-branch dinv-scaled bf16 pairs (g = dinv*x)
__global__ void k_cvt(const float2* __restrict__ x2, const float* __restrict__ dinv,
                      uint* __restrict__ xba, uint* __restrict__ xbb, int n) {
    int i = blockIdx.x * blockDim.x + threadIdx.x;
    if (i >= n * 64) return;
    int node = i >> 6;
    float da = dinv[node], db = dinv[n + node];
    float2 v = x2[i];
    xba[i] = (uint)f2bf(da * v.x) | ((uint)f2bf(da * v.y) << 16);
    xbb[i] = (uint)f2bf(db * v.x) | ((uint)f2bf(db * v.y) << 16);
}

// all 4 weights -> MFMA-frag split-bf16 packing
__global__ void k_pack_all(const float* __restrict__ W0, const float* __restrict__ W1,
                           const float* __restrict__ W2, const float* __restrict__ W3,
                           uint* __restrict__ Wp) {
    int i = blockIdx.x * blockDim.x + threadIdx.x;
    if (i >= 4 * 32768) return;
    int seg = i >> 15;
    int r = i & 32767;
    const float* W = seg == 0 ? W0 : seg == 1 ? W1 : seg == 2 ? W2 : W3;
    int N = seg < 2 ? 256 : 128;
    int k = r / N, nn = r - k * N;
    int kt = k >> 5, q = (k & 31) >> 3, jj = k & 7;
    int nt = nn >> 4, ln = q * 16 + (nn & 15);
    int NT = N >> 4;
    Wp[(size_t)seg * 32768 + (((size_t)(kt * NT + nt)) * 64 + ln) * 8 + jj] = pack_split(W[r]);
}

// ---------- gathers: one wave/node, lane = 2 feats, 4-deep batching ----------
__device__ inline void gather_row(const uint* __restrict__ xb, const int* __restrict__ ep,
                                  int m, int lane, float& ax, float& ay) {
    int j = 0;
    for (; j + 4 <= m; j += 4) {
        int4 s4 = *(const int4*)(ep + j);
        uint u0 = xb[(size_t)s4.x * 64 + lane];
        uint u1 = xb[(size_t)s4.y * 64 + lane];
        uint u2 = xb[(size_t)s4.z * 64 + lane];
        uint u3 = xb[(size_t)s4.w * 64 + lane];
        ax += bf2f((ushort)u0) + bf2f((ushort)u1) + bf2f((ushort)u2) + bf2f((ushort)u3);
        ay += bf2f((ushort)(u0 >> 16)) + bf2f((ushort)(u1 >> 16)) +
              bf2f((ushort)(u2 >> 16)) + bf2f((ushort)(u3 >> 16));
    }
    for (; j < m; ++j) {
        uint u = xb[(size_t)ep[j] * 64 + lane];
        ax += bf2f((ushort)u);
        ay += bf2f((ushort)(u >> 16));
    }
}

// layer1, both branches: blocks [0,gb) = branch a, [gb,2gb) = branch b
__global__ __launch_bounds__(256) void k_gather_l1(
    const uint* __restrict__ xba, const uint* __restrict__ xbb,
    const int* __restrict__ csr_a, const int* __restrict__ csr_b,
    const int* __restrict__ noff, const float* __restrict__ dinv,
    uint* __restrict__ ta, uint* __restrict__ tb, int n, int gb) {
    int bid = blockIdx.x;
    int br = bid >= gb;
    const uint* xb = br ? xbb : xba;
    const int* csr = br ? csr_b : csr_a;
    const int* no = noff + (size_t)br * (n + 1);
    const float* dv = dinv + (size_t)br * n;
    uint* outp = br ? tb : ta;
    int node = ((bid - (br ? gb : 0)) * 256 + (int)threadIdx.x) >> 6;
    if (node >= n) return;
    node = __builtin_amdgcn_readfirstlane(node);
    const int lane = threadIdx.x & 63;
    int beg = no[node], m = no[node + 1] - beg;
    float ax = 0.f, ay = 0.f;
    gather_row(xb, csr + beg, m, lane, ax, ay);
    uint us = xb[(size_t)node * 64 + lane];
    float di = dv[node];
    uint2 o;
    o.x = pack_split(di * (ax + bf2f((ushort)us)));
    o.y = pack_split(di * (ay + bf2f((ushort)(us >> 16))));
    *(uint2*)(outp + (size_t)node * 128 + lane * 2) = o;
}

// layer2, BOTH branches + bias; single write pass over out.
__global__ __launch_bounds__(256) void k_gather_l2(
    const uint* __restrict__ hba, const uint* __restrict__ hbb,
    const int* __restrict__ csr_a, const int* __restrict__ csr_b,
    const int* __restrict__ noff, const float* __restrict__ dinv,
    const float* __restrict__ b2, const float* __restrict__ b3,
    float* __restrict__ out, int n) {
    int node = (blockIdx.x * 256 + (int)threadIdx.x) >> 6;
    if (node >= n) return;
    node = __builtin_amdgcn_readfirstlane(node);
    const int lane = threadIdx.x & 63;

    int beg = noff[node], m = noff[node + 1] - beg;
    float ax = 0.f, ay = 0.f;
    gather_row(hba, csr_a + beg, m, lane, ax, ay);
    uint usa = hba[(size_t)node * 64 + lane];
    float da = dinv[node];
    float vx = da * (ax + bf2f((ushort)usa));
    float vy = da * (ay + bf2f((ushort)(usa >> 16)));

    const int* no_b = noff + (n + 1);
    int beg2 = no_b[node], m2 = no_b[node + 1] - beg2;
    float bx = 0.f, by = 0.f;
    gather_row(hbb, csr_b + beg2, m2, lane, bx, by);
    uint usb = hbb[(size_t)node * 64 + lane];
    float db = dinv[n + node];
    vx += db * (bx + bf2f((ushort)usb));
    vy += db * (by + bf2f((ushort)(usb >> 16)));

    const int f = lane * 2;
    float2 o;
    o.x = b2[f] + b3[f] + vx;
    o.y = b2[f + 1] + b3[f + 1] + vy;
    *(float2*)(out + (size_t)node * 128 + f) = o;
}

// ---------- MFMA GEMM (split-bf16, 3 MFMA/term) ----------
// MODE 0: +bias, relu, write packed split uint. MODE 1: scale by aux[row], write bf16.
template <int K, int NT_TOTAL, int MODE>
__global__ __launch_bounds__(256) void k_gemm_mfma(
    const uint* __restrict__ Ap, const uint* __restrict__ Wp,
    const float* __restrict__ aux, void* __restrict__ Cout, int n) {
    const int lane = threadIdx.x & 63;
    const int wave = threadIdx.x >> 6;
    const int l15 = lane & 15;
    const int quad = lane >> 4;
    const int m_base = blockIdx.y * 128 + (wave >> 1) * 64;
    const int n_base = blockIdx.x * 128 + (wave & 1) * 64;
    const int N = NT_TOTAL * 16;

    f4_t acc[4][4];
#pragma unroll
    for (int a = 0; a < 4; ++a)
#pragma unroll
        for (int b = 0; b < 4; ++b) acc[a][b] = (f4_t){0.f, 0.f, 0.f, 0.f};

#pragma unroll
    for (int kt = 0; kt < K / 32; ++kt) {
        bf8_t ahi[4], alo[4];
#pragma unroll
        for (int mi = 0; mi < 4; ++mi) {
            int row = m_base + mi * 16 + l15;
            uint4 u0 = {0, 0, 0, 0}, u1 = {0, 0, 0, 0};
            if (row < n) {
                const uint* p = Ap + (size_t)row * K + kt * 32 + quad * 8;
                u0 = *(const uint4*)p;
                u1 = *(const uint4*)(p + 4);
            }
            uint ua[8] = {u0.x, u0.y, u0.z, u0.w, u1.x, u1.y, u1.z, u1.w};
#pragma unroll
            for (int j = 0; j < 8; ++j) {
                ahi[mi][j] = (short)(ua[j] & 0xffff);
                alo[mi][j] = (short)(ua[j] >> 16);
            }
        }
#pragma unroll
        for (int nj = 0; nj < 4; ++nj) {
            int nt = (n_base >> 4) + nj;
            const uint* p = Wp + (((size_t)kt * NT_TOTAL + nt) * 64 + lane) * 8;
            uint4 w0 = *(const uint4*)p;
            uint4 w1 = *(const uint4*)(p + 4);
            uint wa[8] = {w0.x, w0.y, w0.z, w0.w, w1.x, w1.y, w1.z, w1.w};
            bf8_t bhi, blo;
#pragma unroll
            for (int j = 0; j < 8; ++j) {
                bhi[j] = (short)(wa[j] & 0xffff);
                blo[j] = (short)(wa[j] >> 16);
            }
#pragma unroll
            for (int mi = 0; mi < 4; ++mi) {
                acc[mi][nj] = __builtin_amdgcn_mfma_f32_16x16x32_bf16(ahi[mi], bhi, acc[mi][nj], 0, 0, 0);
                acc[mi][nj] = __builtin_amdgcn_mfma_f32_16x16x32_bf16(ahi[mi], blo, acc[mi][nj], 0, 0, 0);
                acc[mi][nj] = __builtin_amdgcn_mfma_f32_16x16x32_bf16(alo[mi], bhi, acc[mi][nj], 0, 0, 0);
            }
        }
    }

#pragma unroll
    for (int nj = 0; nj < 4; ++nj) {
        int col = n_base + nj * 16 + l15;
        float bv = 0.f;
        if (MODE == 0) bv = aux[col];
#pragma unroll
        for (int mi = 0; mi < 4; ++mi) {
#pragma unroll
            for (int r = 0; r < 4; ++r) {
                int row = m_base + mi * 16 + quad * 4 + r;
                if (row < n) {
                    float v = acc[mi][nj][r];
                    if (MODE == 0) {
                        v = fmaxf(v + bv, 0.f);
                        ((uint*)Cout)[(size_t)row * N + col] = pack_split(v);
                    } else {
                        v *= aux[row];  // write g = dinv*h
                        ((ushort*)Cout)[(size_t)row * N + col] = f2bf(v);
                    }
                }
            }
        }
    }
}

extern "C" void kernel_launch(void* const* d_in, const int* in_sizes, int n_in,
                              void* d_out, int out_size, void* d_ws, size_t ws_size,
                              hipStream_t stream) {
    const float* x    = (const float*)d_in[0];
    const int*   ei_a = (const int*)d_in[1];
    const int*   ei_b = (const int*)d_in[2];
    const float* W0 = (const float*)d_in[3];
    const float* b0 = (const float*)d_in[4];
    const float* W1 = (const float*)d_in[5];
    const float* b1 = (const float*)d_in[6];
    const float* W2 = (const float*)d_in[7];
    const float* b2 = (const float*)d_in[8];
    const float* W3 = (const float*)d_in[9];
    const float* b3 = (const float*)d_in[10];
    float* out = (float*)d_out;

    const int n = in_sizes[0] / 128;  // 50000
    const int e = in_sizes[1] / 2;    // 800000
    const int NB = (n + 63) / 64;     // 782
    const int NW = (e + CHUNK - 1) / CHUNK;  // 49 (must be <= 64)

    // workspace (~143 MB)
    float* ws      = (float*)d_ws;
    float* dinv    = ws;                              // 2n
    uint*  ta      = (uint*)(ws + 2 * (size_t)n);     // 128n
    uint*  tb      = ta + 128 * (size_t)n;            // 128n
    uint*  t256p   = tb + 128 * (size_t)n;            // 256n
    uint*  xba     = t256p + 256 * (size_t)n;         // 64n
    uint*  xbb     = xba + 64 * (size_t)n;            // 64n
    uint*  Wp      = xbb + 64 * (size_t)n;            // 4*32768
    int*   cnt_mat = (int*)(Wp + 4 * 32768);          // 2*NW*NB
    int*   wgoff   = cnt_mat + 2 * (size_t)NW * NB;   // 2*NB*64
    int*   btot    = wgoff + 2 * (size_t)NB * 64;     // 2*NB
    int*   boff    = btot + 2 * NB;                   // 2*(NB+1)
    int*   noff    = boff + 2 * (NB + 1);             // 2*(n+1)
    int*   ebuf_a  = noff + 2 * (n + 1);              // e
    int*   ebuf_b  = ebuf_a + e;                      // e
    int*   csr_a   = ebuf_b + e;                      // e
    int*   csr_b   = csr_a + e;                       // e
    ushort* tba = (ushort*)ta;
    ushort* tbb = (ushort*)tb;

    const int B = 256;

    // --- CSR build (atomic-free, sequential writes) ---
    k_p1_hist<<<2 * NW, B, 0, stream>>>(ei_a, ei_b, cnt_mat, e, NB, NW);
    k_p2a<<<(2 * NB + 3) / 4, B, 0, stream>>>(cnt_mat, wgoff, btot, NB, NW);
    k_p2b<<<1, B, 0, stream>>>(btot, boff, NB, e);
    k_p3_scatter<<<2 * NW, B, 0, stream>>>(ei_a, ei_b, wgoff, boff, ebuf_a, ebuf_b, e, NB, NW);
    k_p4_nodesort<<<2 * NB, B, 0, stream>>>(ebuf_a, ebuf_b, boff, csr_a, csr_b, noff, dinv,
                                            n, e, NB);

    // --- conversions ---
    k_cvt<<<(n * 64 + B - 1) / B, B, 0, stream>>>((const float2*)x, dinv, xba, xbb, n);
    k_pack_all<<<(4 * 32768 + B - 1) / B, B, 0, stream>>>(W0, W1, W2, W3, Wp);

    const int gb = (n + 3) / 4;
    const int mblocks = (n + 127) / 128;

    k_gather_l1<<<2 * gb, B, 0, stream>>>(xba, xbb, csr_a, csr_b, noff, dinv, ta, tb, n, gb);

    // branch a GEMMs
    k_gemm_mfma<128, 16, 0><<<dim3(2, mblocks), B, 0, stream>>>(ta, Wp, b0, (void*)t256p, n);
    k_gemm_mfma<256, 8, 1><<<dim3(1, mblocks), B, 0, stream>>>(t256p, Wp + 2 * 32768, dinv,
                                                               (void*)tba, n);
    // branch b GEMMs
    k_gemm_mfma<128, 16, 0><<<dim3(2, mblocks), B, 0, stream>>>(tb, Wp + 32768, b1,
                                                                (void*)t256p, n);
    k_gemm_mfma<256, 8, 1><<<dim3(1, mblocks), B, 0, stream>>>(t256p, Wp + 3 * 32768,
                                                               dinv + n, (void*)tbb, n);

    // final: out = b2+b3 + agg_a + agg_b, single pass
    k_gather_l2<<<gb, B, 0, stream>>>((const uint*)tba, (const uint*)tbb, csr_a, csr_b,
                                      noff, dinv, b2, b3, out, n);
}

// Round 7
// 394.211 us; speedup vs baseline: 14.5403x; 1.1820x over previous
//
#include <hip/hip_runtime.h>

// GCN ensemble: atomic-free counting-sort CSR + bf16 gathers + FUSED per-branch MLP
// (gemm1 -> LDS bf16 -> gemm2) in MFMA. t256 intermediate never touches HBM
// (saves ~150MB/branch vs separate GEMMs; R6 gathers measured at 45% HBM on pure
// random 256B reads = near random-access ceiling).
// Math: agg[d] = dinv_d * (sum_s g[s] + g[d]), g = dinv*h; dinv folded out of edges.

typedef unsigned int uint;
typedef unsigned short ushort;
typedef __attribute__((ext_vector_type(8))) short bf8_t;
typedef __attribute__((ext_vector_type(4))) float f4_t;

#define CHUNK 16384  // edges per WG in P1/P3; NW = ceil(e/CHUNK) must be <= 64
#define MAXNB 800    // max buckets (n <= 51200)

__device__ inline ushort f2bf(float f) {
    uint u = __float_as_uint(f);
    return (ushort)((u + 0x7fff + ((u >> 16) & 1)) >> 16);
}
__device__ inline float bf2f(ushort h) { return __uint_as_float(((uint)h) << 16); }
__device__ inline uint pack_split(float f) {
    ushort hi = f2bf(f);
    ushort lo = f2bf(f - bf2f(hi));
    return (uint)hi | ((uint)lo << 16);
}

// ---------- P1: per-chunk bucket histogram (LDS), dense writes ----------
__global__ __launch_bounds__(256) void k_p1_hist(
    const int* __restrict__ ei_a, const int* __restrict__ ei_b,
    int* __restrict__ cnt_mat, int e, int NB, int NW) {
    __shared__ int lh[MAXNB];
    int l = blockIdx.x / NW, w = blockIdx.x % NW;
    const int* dst = (l ? ei_b : ei_a) + e;
    for (int t = threadIdx.x; t < NB; t += 256) lh[t] = 0;
    __syncthreads();
    int beg = w * CHUNK, end = min(beg + CHUNK, e);
    for (int j = beg + threadIdx.x; j < end; j += 256) atomicAdd(&lh[dst[j] >> 6], 1);
    __syncthreads();
    int* outp = cnt_mat + ((size_t)l * NW + w) * NB;
    for (int t = threadIdx.x; t < NB; t += 256) outp[t] = lh[t];
}

// ---------- P2a: per-bucket exclusive prefix over WGs (one wave per bucket) ----------
__global__ __launch_bounds__(256) void k_p2a(const int* __restrict__ cnt_mat,
                                             int* __restrict__ wgoff, int* __restrict__ btot,
                                             int NB, int NW) {
    int which = blockIdx.x * 4 + ((int)threadIdx.x >> 6);
    if (which >= 2 * NB) return;
    int lane = threadIdx.x & 63;
    int l = which / NB, b = which - l * NB;
    int v = (lane < NW) ? cnt_mat[((size_t)l * NW + lane) * NB + b] : 0;
    int s = v;
#pragma unroll
    for (int o = 1; o < 64; o <<= 1) {
        int t = __shfl_up(s, o, 64);
        if (lane >= o) s += t;
    }
    if (lane < NW) wgoff[((size_t)l * NB + b) * 64 + lane] = s - v;
    if (lane == 63) btot[which] = s;
}

// ---------- P2b: exclusive scan of bucket totals per list (one WG) ----------
__global__ __launch_bounds__(256) void k_p2b(const int* __restrict__ btot,
                                             int* __restrict__ boff, int NB, int e) {
    __shared__ int s[1024];
    for (int l = 0; l < 2; ++l) {
        for (int t = threadIdx.x; t < 1024; t += 256) s[t] = (t < NB) ? btot[l * NB + t] : 0;
        __syncthreads();
        for (int o = 1; o < 1024; o <<= 1) {
            int tmp[4];
#pragma unroll
            for (int k = 0; k < 4; ++k) {
                int idx = threadIdx.x + k * 256;
                tmp[k] = (idx >= o) ? s[idx - o] : 0;
            }
            __syncthreads();
#pragma unroll
            for (int k = 0; k < 4; ++k) s[threadIdx.x + k * 256] += tmp[k];
            __syncthreads();
        }
        for (int t = threadIdx.x; t < NB; t += 256)
            boff[l * (NB + 1) + t] = s[t] - btot[l * NB + t];
        if (threadIdx.x == 0) boff[l * (NB + 1) + NB] = e;
        __syncthreads();
    }
}

// ---------- P3: scatter packed entries into contiguous per-(WG,bucket) segments ----------
__global__ __launch_bounds__(256) void k_p3_scatter(
    const int* __restrict__ ei_a, const int* __restrict__ ei_b,
    const int* __restrict__ wgoff, const int* __restrict__ boff,
    int* __restrict__ ebuf_a, int* __restrict__ ebuf_b, int e, int NB, int NW) {
    __shared__ int base[MAXNB];
    __shared__ int bump[MAXNB];
    int l = blockIdx.x / NW, w = blockIdx.x % NW;
    const int* ei = l ? ei_b : ei_a;
    int* ebuf = l ? ebuf_b : ebuf_a;
    for (int t = threadIdx.x; t < NB; t += 256) {
        base[t] = boff[l * (NB + 1) + t] + wgoff[((size_t)l * NB + t) * 64 + w];
        bump[t] = 0;
    }
    __syncthreads();
    int beg = w * CHUNK, end = min(beg + CHUNK, e);
    for (int j = beg + threadIdx.x; j < end; j += 256) {
        int sv = ei[j], d = ei[e + j];
        int b = d >> 6;
        int pos = base[b] + atomicAdd(&bump[b], 1);
        ebuf[pos] = ((d & 63) << 17) | sv;
    }
}

// ---------- P4: within-bucket node sort -> final CSR + noff + dinv ----------
__global__ __launch_bounds__(256) void k_p4_nodesort(
    const int* __restrict__ ebuf_a, const int* __restrict__ ebuf_b,
    const int* __restrict__ boff, int* __restrict__ csr_a, int* __restrict__ csr_b,
    int* __restrict__ noff, float* __restrict__ dinv, int n, int e, int NB) {
    __shared__ int hist[64], nstart[64];
    int which = blockIdx.x;
    int l = which / NB, b = which - l * NB;
    const int* ebuf = l ? ebuf_b : ebuf_a;
    int* csr = l ? csr_b : csr_a;
    int seg0 = boff[l * (NB + 1) + b], seg1 = boff[l * (NB + 1) + b + 1];
    if (threadIdx.x < 64) hist[threadIdx.x] = 0;
    __syncthreads();
    for (int j = seg0 + (int)threadIdx.x; j < seg1; j += 256)
        atomicAdd(&hist[ebuf[j] >> 17], 1);
    __syncthreads();
    if (threadIdx.x < 64) {
        int v = hist[threadIdx.x];
        int s = v;
#pragma unroll
        for (int o = 1; o < 64; o <<= 1) {
            int t = __shfl_up(s, o, 64);
            if ((int)threadIdx.x >= o) s += t;
        }
        int node = b * 64 + (int)threadIdx.x;
        nstart[threadIdx.x] = seg0 + s - v;
        if (node < n) {
            noff[(size_t)l * (n + 1) + node] = seg0 + s - v;
            dinv[(size_t)l * n + node] = rsqrtf((float)v + 1.0f);
        }
        hist[threadIdx.x] = 0;  // reuse as bump counter
    }
    if (b == NB - 1 && threadIdx.x == 0) noff[(size_t)l * (n + 1) + n] = e;
    __syncthreads();
    for (int j = seg0 + (int)threadIdx.x; j < seg1; j += 256) {
        int pk = ebuf[j];
        int ni = pk >> 17;
        int pos = nstart[ni] + atomicAdd(&hist[ni], 1);
        csr[pos] = pk & 0x1ffff;
    }
}

// ---------- conversions ----------
__global__ void k_cvt(const float2* __restrict__ x2, const float* __restrict__ dinv,
                      uint* __restrict__ xba, uint* __restrict__ xbb, int n) {
    int i = blockIdx.x * blockDim.x + threadIdx.x;
    if (i >= n * 64) return;
    int node = i >> 6;
    float da = dinv[node], db = dinv[n + node];
    float2 v = x2[i];
    xba[i] = (uint)f2bf(da * v.x) | ((uint)f2bf(da * v.y) << 16);
    xbb[i] = (uint)f2bf(db * v.x) | ((uint)f2bf(db * v.y) << 16);
}

// all 4 weights -> MFMA-frag split-bf16 packing
__global__ void k_pack_all(const float* __restrict__ W0, const float* __restrict__ W1,
                           const float* __restrict__ W2, const float* __restrict__ W3,
                           uint* __restrict__ Wp) {
    int i = blockIdx.x * blockDim.x + threadIdx.x;
    if (i >= 4 * 32768) return;
    int seg = i >> 15;
    int r = i & 32767;
    const float* W = seg == 0 ? W0 : seg == 1 ? W1 : seg == 2 ? W2 : W3;
    int N = seg < 2 ? 256 : 128;
    int k = r / N, nn = r - k * N;
    int kt = k >> 5, q = (k & 31) >> 3, jj = k & 7;
    int nt = nn >> 4, ln = q * 16 + (nn & 15);
    int NT = N >> 4;
    Wp[(size_t)seg * 32768 + (((size_t)(kt * NT + nt)) * 64 + ln) * 8 + jj] = pack_split(W[r]);
}

// ---------- gathers: one wave/node, lane = 2 feats, 8-deep batching ----------
__device__ inline void gather_row(const uint* __restrict__ xb, const int* __restrict__ ep,
                                  int m, int lane, float& ax, float& ay) {
    int j = 0;
    for (; j + 8 <= m; j += 8) {
        int4 s4 = *(const int4*)(ep + j);
        int4 s5 = *(const int4*)(ep + j + 4);
        uint u0 = xb[(size_t)s4.x * 64 + lane];
        uint u1 = xb[(size_t)s4.y * 64 + lane];
        uint u2 = xb[(size_t)s4.z * 64 + lane];
        uint u3 = xb[(size_t)s4.w * 64 + lane];
        uint u4 = xb[(size_t)s5.x * 64 + lane];
        uint u5 = xb[(size_t)s5.y * 64 + lane];
        uint u6 = xb[(size_t)s5.z * 64 + lane];
        uint u7 = xb[(size_t)s5.w * 64 + lane];
        ax += bf2f((ushort)u0) + bf2f((ushort)u1) + bf2f((ushort)u2) + bf2f((ushort)u3) +
              bf2f((ushort)u4) + bf2f((ushort)u5) + bf2f((ushort)u6) + bf2f((ushort)u7);
        ay += bf2f((ushort)(u0 >> 16)) + bf2f((ushort)(u1 >> 16)) +
              bf2f((ushort)(u2 >> 16)) + bf2f((ushort)(u3 >> 16)) +
              bf2f((ushort)(u4 >> 16)) + bf2f((ushort)(u5 >> 16)) +
              bf2f((ushort)(u6 >> 16)) + bf2f((ushort)(u7 >> 16));
    }
    for (; j + 4 <= m; j += 4) {
        int4 s4 = *(const int4*)(ep + j);
        uint u0 = xb[(size_t)s4.x * 64 + lane];
        uint u1 = xb[(size_t)s4.y * 64 + lane];
        uint u2 = xb[(size_t)s4.z * 64 + lane];
        uint u3 = xb[(size_t)s4.w * 64 + lane];
        ax += bf2f((ushort)u0) + bf2f((ushort)u1) + bf2f((ushort)u2) + bf2f((ushort)u3);
        ay += bf2f((ushort)(u0 >> 16)) + bf2f((ushort)(u1 >> 16)) +
              bf2f((ushort)(u2 >> 16)) + bf2f((ushort)(u3 >> 16));
    }
    for (; j < m; ++j) {
        uint u = xb[(size_t)ep[j] * 64 + lane];
        ax += bf2f((ushort)u);
        ay += bf2f((ushort)(u >> 16));
    }
}

// layer1, both branches: blocks [0,gb) = branch a, [gb,2gb) = branch b
__global__ __launch_bounds__(256) void k_gather_l1(
    const uint* __restrict__ xba, const uint* __restrict__ xbb,
    const int* __restrict__ csr_a, const int* __restrict__ csr_b,
    const int* __restrict__ noff, const float* __restrict__ dinv,
    uint* __restrict__ ta, uint* __restrict__ tb, int n, int gb) {
    int bid = blockIdx.x;
    int br = bid >= gb;
    const uint* xb = br ? xbb : xba;
    const int* csr = br ? csr_b : csr_a;
    const int* no = noff + (size_t)br * (n + 1);
    const float* dv = dinv + (size_t)br * n;
    uint* outp = br ? tb : ta;
    int node = ((bid - (br ? gb : 0)) * 256 + (int)threadIdx.x) >> 6;
    if (node >= n) return;
    node = __builtin_amdgcn_readfirstlane(node);
    const int lane = threadIdx.x & 63;
    int beg = no[node], m = no[node + 1] - beg;
    uint us = xb[(size_t)node * 64 + lane];
    float ax = 0.f, ay = 0.f;
    gather_row(xb, csr + beg, m, lane, ax, ay);
    float di = dv[node];
    uint2 o;
    o.x = pack_split(di * (ax + bf2f((ushort)us)));
    o.y = pack_split(di * (ay + bf2f((ushort)(us >> 16))));
    *(uint2*)(outp + (size_t)node * 128 + lane * 2) = o;
}

// layer2, BOTH branches + bias; single write pass over out.
__global__ __launch_bounds__(256) void k_gather_l2(
    const uint* __restrict__ hba, const uint* __restrict__ hbb,
    const int* __restrict__ csr_a, const int* __restrict__ csr_b,
    const int* __restrict__ noff, const float* __restrict__ dinv,
    const float* __restrict__ b2, const float* __restrict__ b3,
    float* __restrict__ out, int n) {
    int node = (blockIdx.x * 256 + (int)threadIdx.x) >> 6;
    if (node >= n) return;
    node = __builtin_amdgcn_readfirstlane(node);
    const int lane = threadIdx.x & 63;

    int beg = noff[node], m = noff[node + 1] - beg;
    float ax = 0.f, ay = 0.f;
    gather_row(hba, csr_a + beg, m, lane, ax, ay);
    uint usa = hba[(size_t)node * 64 + lane];
    float da = dinv[node];
    float vx = da * (ax + bf2f((ushort)usa));
    float vy = da * (ay + bf2f((ushort)(usa >> 16)));

    const int* no_b = noff + (n + 1);
    int beg2 = no_b[node], m2 = no_b[node + 1] - beg2;
    float bx = 0.f, by = 0.f;
    gather_row(hbb, csr_b + beg2, m2, lane, bx, by);
    uint usb = hbb[(size_t)node * 64 + lane];
    float db = dinv[n + node];
    vx += db * (bx + bf2f((ushort)usb));
    vy += db * (by + bf2f((ushort)(usb >> 16)));

    const int f = lane * 2;
    float2 o;
    o.x = b2[f] + b3[f] + vx;
    o.y = b2[f + 1] + b3[f + 1] + vy;
    *(float2*)(out + (size_t)node * 128 + f) = o;
}

// ---------- FUSED MLP: h = relu(A@W1+b) -> LDS bf16 -> C = (h@W2)*dinv ----------
// A: split-packed uint [n,128]. Block = 128 rows. Stage1: wave tile 64x128 of h[128,256]
// (3 MFMA/term, split A & W). Stage2: wave tile 64x64 of C[128,128] (2 MFMA, bf16 A from
// LDS, split W). LDS row stride 264 bf16 (528B -> 2-way bank alias = free, 16B aligned).
__global__ __launch_bounds__(256) void k_mlp_fused(
    const uint* __restrict__ ta, const uint* __restrict__ tb,
    const uint* __restrict__ Wp, const float* __restrict__ b0,
    const float* __restrict__ b1, const float* __restrict__ dinv,
    ushort* __restrict__ oa, ushort* __restrict__ ob, int n) {
    constexpr int LDW = 264;
    __shared__ ushort hs[128 * LDW];  // 67.6 KB
    const int br = blockIdx.y;
    const uint* Ap   = br ? tb : ta;
    const uint* Wp1  = Wp + (br ? 32768 : 0);
    const uint* Wp2  = Wp + (br ? 3 * 32768 : 2 * 32768);
    const float* bias = br ? b1 : b0;
    const float* dv  = dinv + (br ? n : 0);
    ushort* Cout     = br ? ob : oa;

    const int lane = threadIdx.x & 63;
    const int wave = threadIdx.x >> 6;
    const int l15 = lane & 15;
    const int quad = lane >> 4;
    const int row_blk = blockIdx.x * 128;

    // ---- stage 1 ----
    {
        const int m_base = (wave >> 1) * 64;
        const int n_base = (wave & 1) * 128;
        f4_t acc[4][8];
#pragma unroll
        for (int a = 0; a < 4; ++a)
#pragma unroll
            for (int b = 0; b < 8; ++b) acc[a][b] = (f4_t){0.f, 0.f, 0.f, 0.f};

#pragma unroll
        for (int kt = 0; kt < 4; ++kt) {
            bf8_t ahi[4], alo[4];
#pragma unroll
            for (int mi = 0; mi < 4; ++mi) {
                int row = row_blk + m_base + mi * 16 + l15;
                uint4 u0 = {0, 0, 0, 0}, u1 = {0, 0, 0, 0};
                if (row < n) {
                    const uint* p = Ap + (size_t)row * 128 + kt * 32 + quad * 8;
                    u0 = *(const uint4*)p;
                    u1 = *(const uint4*)(p + 4);
                }
                uint ua[8] = {u0.x, u0.y, u0.z, u0.w, u1.x, u1.y, u1.z, u1.w};
#pragma unroll
                for (int j = 0; j < 8; ++j) {
                    ahi[mi][j] = (short)(ua[j] & 0xffff);
                    alo[mi][j] = (short)(ua[j] >> 16);
                }
            }
#pragma unroll
            for (int nj = 0; nj < 8; ++nj) {
                int nt = (n_base >> 4) + nj;
                const uint* p = Wp1 + (((size_t)(kt * 16 + nt)) * 64 + lane) * 8;
                uint4 w0 = *(const uint4*)p;
                uint4 w1 = *(const uint4*)(p + 4);
                uint wa[8] = {w0.x, w0.y, w0.z, w0.w, w1.x, w1.y, w1.z, w1.w};
                bf8_t bhi, blo;
#pragma unroll
                for (int j = 0; j < 8; ++j) {
                    bhi[j] = (short)(wa[j] & 0xffff);
                    blo[j] = (short)(wa[j] >> 16);
                }
#pragma unroll
                for (int mi = 0; mi < 4; ++mi) {
                    acc[mi][nj] = __builtin_amdgcn_mfma_f32_16x16x32_bf16(ahi[mi], bhi, acc[mi][nj], 0, 0, 0);
                    acc[mi][nj] = __builtin_amdgcn_mfma_f32_16x16x32_bf16(ahi[mi], blo, acc[mi][nj], 0, 0, 0);
                    acc[mi][nj] = __builtin_amdgcn_mfma_f32_16x16x32_bf16(alo[mi], bhi, acc[mi][nj], 0, 0, 0);
                }
            }
        }
        // epilogue 1 -> LDS (relu + bias, bf16)
#pragma unroll
        for (int nj = 0; nj < 8; ++nj) {
            int col = n_base + nj * 16 + l15;
            float bv = bias[col];
#pragma unroll
            for (int mi = 0; mi < 4; ++mi) {
#pragma unroll
                for (int r = 0; r < 4; ++r) {
                    int rl = m_base + mi * 16 + quad * 4 + r;
                    float v = fmaxf(acc[mi][nj][r] + bv, 0.f);
                    hs[rl * LDW + col] = f2bf(v);
                }
            }
        }
    }
    __syncthreads();

    // ---- stage 2 ----
    {
        const int m2 = (wave >> 1) * 64;
        const int n2 = (wave & 1) * 64;
        f4_t acc2[4][4];
#pragma unroll
        for (int a = 0; a < 4; ++a)
#pragma unroll
            for (int b = 0; b < 4; ++b) acc2[a][b] = (f4_t){0.f, 0.f, 0.f, 0.f};

#pragma unroll
        for (int kt = 0; kt < 8; ++kt) {
            bf8_t a2[4];
#pragma unroll
            for (int mi = 0; mi < 4; ++mi) {
                int rl = m2 + mi * 16 + l15;
                a2[mi] = *(const bf8_t*)&hs[rl * LDW + kt * 32 + quad * 8];
            }
#pragma unroll
            for (int nj = 0; nj < 4; ++nj) {
                int nt = (n2 >> 4) + nj;
                const uint* p = Wp2 + (((size_t)(kt * 8 + nt)) * 64 + lane) * 8;
                uint4 w0 = *(const uint4*)p;
                uint4 w1 = *(const uint4*)(p + 4);
                uint wa[8] = {w0.x, w0.y, w0.z, w0.w, w1.x, w1.y, w1.z, w1.w};
                bf8_t bhi, blo;
#pragma unroll
                for (int j = 0; j < 8; ++j) {
                    bhi[j] = (short)(wa[j] & 0xffff);
                    blo[j] = (short)(wa[j] >> 16);
                }
#pragma unroll
                for (int mi = 0; mi < 4; ++mi) {
                    acc2[mi][nj] = __builtin_amdgcn_mfma_f32_16x16x32_bf16(a2[mi], bhi, acc2[mi][nj], 0, 0, 0);
                    acc2[mi][nj] = __builtin_amdgcn_mfma_f32_16x16x32_bf16(a2[mi], blo, acc2[mi][nj], 0, 0, 0);
                }
            }
        }
        // epilogue 2: scale by dinv[row], write bf16 g = dinv*h2
#pragma unroll
        for (int nj = 0; nj < 4; ++nj) {
            int col = n2 + nj * 16 + l15;
#pragma unroll
            for (int mi = 0; mi < 4; ++mi) {
#pragma unroll
                for (int r = 0; r < 4; ++r) {
                    int row = row_blk + m2 + mi * 16 + quad * 4 + r;
                    if (row < n) {
                        float v = acc2[mi][nj][r] * dv[row];
                        Cout[(size_t)row * 128 + col] = f2bf(v);
                    }
                }
            }
        }
    }
}

extern "C" void kernel_launch(void* const* d_in, const int* in_sizes, int n_in,
                              void* d_out, int out_size, void* d_ws, size_t ws_size,
                              hipStream_t stream) {
    const float* x    = (const float*)d_in[0];
    const int*   ei_a = (const int*)d_in[1];
    const int*   ei_b = (const int*)d_in[2];
    const float* W0 = (const float*)d_in[3];
    const float* b0 = (const float*)d_in[4];
    const float* W1 = (const float*)d_in[5];
    const float* b1 = (const float*)d_in[6];
    const float* W2 = (const float*)d_in[7];
    const float* b2 = (const float*)d_in[8];
    const float* W3 = (const float*)d_in[9];
    const float* b3 = (const float*)d_in[10];
    float* out = (float*)d_out;

    const int n = in_sizes[0] / 128;  // 50000
    const int e = in_sizes[1] / 2;    // 800000
    const int NB = (n + 63) / 64;     // 782
    const int NW = (e + CHUNK - 1) / CHUNK;  // 49 (<= 64)

    // workspace (~116 MB)
    float* ws      = (float*)d_ws;
    float* dinv    = ws;                              // 2n
    uint*  ta      = (uint*)(ws + 2 * (size_t)n);     // 128n (split t128, branch a)
    uint*  tb      = ta + 128 * (size_t)n;            // 128n
    uint*  xba     = tb + 128 * (size_t)n;            // 64n
    uint*  xbb     = xba + 64 * (size_t)n;            // 64n
    uint*  oa      = xbb + 64 * (size_t)n;            // 64n (bf16 g, branch a)
    uint*  ob      = oa + 64 * (size_t)n;             // 64n
    uint*  Wp      = ob + 64 * (size_t)n;             // 4*32768
    int*   cnt_mat = (int*)(Wp + 4 * 32768);          // 2*NW*NB
    int*   wgoff   = cnt_mat + 2 * (size_t)NW * NB;   // 2*NB*64
    int*   btot    = wgoff + 2 * (size_t)NB * 64;     // 2*NB
    int*   boff    = btot + 2 * NB;                   // 2*(NB+1)
    int*   noff    = boff + 2 * (NB + 1);             // 2*(n+1)
    int*   ebuf_a  = noff + 2 * (n + 1);              // e
    int*   ebuf_b  = ebuf_a + e;                      // e
    int*   csr_a   = ebuf_b + e;                      // e
    int*   csr_b   = csr_a + e;                       // e

    const int B = 256;

    // --- CSR build (atomic-free, sequential writes) ---
    k_p1_hist<<<2 * NW, B, 0, stream>>>(ei_a, ei_b, cnt_mat, e, NB, NW);
    k_p2a<<<(2 * NB + 3) / 4, B, 0, stream>>>(cnt_mat, wgoff, btot, NB, NW);
    k_p2b<<<1, B, 0, stream>>>(btot, boff, NB, e);
    k_p3_scatter<<<2 * NW, B, 0, stream>>>(ei_a, ei_b, wgoff, boff, ebuf_a, ebuf_b, e, NB, NW);
    k_p4_nodesort<<<2 * NB, B, 0, stream>>>(ebuf_a, ebuf_b, boff, csr_a, csr_b, noff, dinv,
                                            n, e, NB);

    // --- conversions ---
    k_cvt<<<(n * 64 + B - 1) / B, B, 0, stream>>>((const float2*)x, dinv, xba, xbb, n);
    k_pack_all<<<(4 * 32768 + B - 1) / B, B, 0, stream>>>(W0, W1, W2, W3, Wp);

    const int gb = (n + 3) / 4;
    const int mblocks = (n + 127) / 128;

    // layer-1 aggregation, both branches
    k_gather_l1<<<2 * gb, B, 0, stream>>>(xba, xbb, csr_a, csr_b, noff, dinv, ta, tb, n, gb);

    // fused MLP (gemm1 -> LDS -> gemm2), both branches in one dispatch
    k_mlp_fused<<<dim3(mblocks, 2), B, 0, stream>>>(ta, tb, Wp, b0, b1, dinv,
                                                    (ushort*)oa, (ushort*)ob, n);

    // layer-2 aggregation + ensemble sum + bias, single pass over out
    k_gather_l2<<<gb, B, 0, stream>>>(oa, ob, csr_a, csr_b, noff, dinv, b2, b3, out, n);
}

// Round 8
// 314.511 us; speedup vs baseline: 18.2249x; 1.2534x over previous
//
#include <hip/hip_runtime.h>

// GCN ensemble: atomic-free counting-sort CSR (high-parallelism) + bf16 gathers +
// fused MLP (gemm1 -> LDS bf16 -> gemm2), plain bf16 MFMA.
// R7 lessons: (a) split-bf16 3x MFMA wasted — h passes through bf16 LDS anyway;
// (b) 67KB LDS -> 2 blocks/CU -> latency-bound at 8.9% occupancy; now 33.8KB/64-row
// blocks; (c) build chain was 98-block grids (~140us) -> CHUNK=4096, 392-block grids.
// Math: agg[d] = dinv_d * (sum_s g[s] + g[d]), g = dinv*h; dinv folded out of edges.

typedef unsigned int uint;
typedef unsigned short ushort;
typedef __attribute__((ext_vector_type(8))) short bf8_t;
typedef __attribute__((ext_vector_type(4))) float f4_t;

#define CHUNK 4096   // edges per WG in P1/P3; NW = ceil(e/CHUNK) must be <= 256
#define MAXNB 800    // max buckets (n <= 51200)

__device__ inline ushort f2bf(float f) {
    uint u = __float_as_uint(f);
    return (ushort)((u + 0x7fff + ((u >> 16) & 1)) >> 16);
}
__device__ inline float bf2f(ushort h) { return __uint_as_float(((uint)h) << 16); }

// ---------- P1: per-chunk bucket histogram (LDS), dense writes ----------
__global__ __launch_bounds__(256) void k_p1_hist(
    const int* __restrict__ ei_a, const int* __restrict__ ei_b,
    int* __restrict__ cnt_mat, int e, int NB, int NW) {
    __shared__ int lh[MAXNB];
    int l = blockIdx.x / NW, w = blockIdx.x % NW;
    const int* dst = (l ? ei_b : ei_a) + e;
    for (int t = threadIdx.x; t < NB; t += 256) lh[t] = 0;
    __syncthreads();
    int beg = w * CHUNK, end = min(beg + CHUNK, e);
    for (int j = beg + threadIdx.x; j < end; j += 256) atomicAdd(&lh[dst[j] >> 6], 1);
    __syncthreads();
    int* outp = cnt_mat + ((size_t)l * NW + w) * NB;
    for (int t = threadIdx.x; t < NB; t += 256) outp[t] = lh[t];
}

// ---------- P2a: per-bucket exclusive prefix over WGs (one block per bucket) ----------
__global__ __launch_bounds__(256) void k_p2a(const int* __restrict__ cnt_mat,
                                             int* __restrict__ wgoff, int* __restrict__ btot,
                                             int NB, int NW) {
    __shared__ int s[256];
    int which = blockIdx.x;  // 0..2*NB-1
    int l = which / NB, b = which - l * NB;
    int t = threadIdx.x;
    int v = (t < NW) ? cnt_mat[((size_t)l * NW + t) * NB + b] : 0;
    s[t] = v;
    __syncthreads();
    for (int o = 1; o < 256; o <<= 1) {
        int x = 0;
        if (t >= o) x = s[t - o];
        __syncthreads();
        s[t] += x;
        __syncthreads();
    }
    if (t < NW) wgoff[((size_t)l * NB + b) * NW + t] = s[t] - v;
    if (t == 255) btot[which] = s[255];
}

// ---------- P2b: exclusive scan of bucket totals per list (one WG) ----------
__global__ __launch_bounds__(256) void k_p2b(const int* __restrict__ btot,
                                             int* __restrict__ boff, int NB, int e) {
    __shared__ int s[1024];
    for (int l = 0; l < 2; ++l) {
        for (int t = threadIdx.x; t < 1024; t += 256) s[t] = (t < NB) ? btot[l * NB + t] : 0;
        __syncthreads();
        for (int o = 1; o < 1024; o <<= 1) {
            int tmp[4];
#pragma unroll
            for (int k = 0; k < 4; ++k) {
                int idx = threadIdx.x + k * 256;
                tmp[k] = (idx >= o) ? s[idx - o] : 0;
            }
            __syncthreads();
#pragma unroll
            for (int k = 0; k < 4; ++k) s[threadIdx.x + k * 256] += tmp[k];
            __syncthreads();
        }
        for (int t = threadIdx.x; t < NB; t += 256)
            boff[l * (NB + 1) + t] = s[t] - btot[l * NB + t];
        if (threadIdx.x == 0) boff[l * (NB + 1) + NB] = e;
        __syncthreads();
    }
}

// ---------- P3: scatter packed entries into contiguous per-(WG,bucket) segments ----------
__global__ __launch_bounds__(256) void k_p3_scatter(
    const int* __restrict__ ei_a, const int* __restrict__ ei_b,
    const int* __restrict__ wgoff, const int* __restrict__ boff,
    int* __restrict__ ebuf_a, int* __restrict__ ebuf_b, int e, int NB, int NW) {
    __shared__ int base[MAXNB];
    __shared__ int bump[MAXNB];
    int l = blockIdx.x / NW, w = blockIdx.x % NW;
    const int* ei = l ? ei_b : ei_a;
    int* ebuf = l ? ebuf_b : ebuf_a;
    for (int t = threadIdx.x; t < NB; t += 256) {
        base[t] = boff[l * (NB + 1) + t] + wgoff[((size_t)l * NB + t) * NW + w];
        bump[t] = 0;
    }
    __syncthreads();
    int beg = w * CHUNK, end = min(beg + CHUNK, e);
    for (int j = beg + threadIdx.x; j < end; j += 256) {
        int sv = ei[j], d = ei[e + j];
        int b = d >> 6;
        int pos = base[b] + atomicAdd(&bump[b], 1);
        ebuf[pos] = ((d & 63) << 17) | sv;
    }
}

// ---------- P4: within-bucket node sort -> final CSR + noff + dinv ----------
__global__ __launch_bounds__(256) void k_p4_nodesort(
    const int* __restrict__ ebuf_a, const int* __restrict__ ebuf_b,
    const int* __restrict__ boff, int* __restrict__ csr_a, int* __restrict__ csr_b,
    int* __restrict__ noff, float* __restrict__ dinv, int n, int e, int NB) {
    __shared__ int hist[64], nstart[64];
    int which = blockIdx.x;
    int l = which / NB, b = which - l * NB;
    const int* ebuf = l ? ebuf_b : ebuf_a;
    int* csr = l ? csr_b : csr_a;
    int seg0 = boff[l * (NB + 1) + b], seg1 = boff[l * (NB + 1) + b + 1];
    if (threadIdx.x < 64) hist[threadIdx.x] = 0;
    __syncthreads();
    for (int j = seg0 + (int)threadIdx.x; j < seg1; j += 256)
        atomicAdd(&hist[ebuf[j] >> 17], 1);
    __syncthreads();
    if (threadIdx.x < 64) {
        int v = hist[threadIdx.x];
        int s = v;
#pragma unroll
        for (int o = 1; o < 64; o <<= 1) {
            int t = __shfl_up(s, o, 64);
            if ((int)threadIdx.x >= o) s += t;
        }
        int node = b * 64 + (int)threadIdx.x;
        nstart[threadIdx.x] = seg0 + s - v;
        if (node < n) {
            noff[(size_t)l * (n + 1) + node] = seg0 + s - v;
            dinv[(size_t)l * n + node] = rsqrtf((float)v + 1.0f);
        }
        hist[threadIdx.x] = 0;  // reuse as bump counter
    }
    if (b == NB - 1 && threadIdx.x == 0) noff[(size_t)l * (n + 1) + n] = e;
    __syncthreads();
    for (int j = seg0 + (int)threadIdx.x; j < seg1; j += 256) {
        int pk = ebuf[j];
        int ni = pk >> 17;
        int pos = nstart[ni] + atomicAdd(&hist[ni], 1);
        csr[pos] = pk & 0x1ffff;
    }
}

// ---------- conversions ----------
__global__ void k_cvt(const float2* __restrict__ x2, const float* __restrict__ dinv,
                      uint* __restrict__ xba, uint* __restrict__ xbb, int n) {
    int i = blockIdx.x * blockDim.x + threadIdx.x;
    if (i >= n * 64) return;
    int node = i >> 6;
    float da = dinv[node], db = dinv[n + node];
    float2 v = x2[i];
    xba[i] = (uint)f2bf(da * v.x) | ((uint)f2bf(da * v.y) << 16);
    xbb[i] = (uint)f2bf(db * v.x) | ((uint)f2bf(db * v.y) << 16);
}

// all 4 weights -> MFMA-frag plain-bf16 packing (ushort)
// Wpb[seg*32768 + ((kt*NT+nt)*64 + quad*16+(n&15))*8 + (k&7)] = bf16(W[k][n])
__global__ void k_pack_all(const float* __restrict__ W0, const float* __restrict__ W1,
                           const float* __restrict__ W2, const float* __restrict__ W3,
                           ushort* __restrict__ Wpb) {
    int i = blockIdx.x * blockDim.x + threadIdx.x;
    if (i >= 4 * 32768) return;
    int seg = i >> 15;
    int r = i & 32767;
    const float* W = seg == 0 ? W0 : seg == 1 ? W1 : seg == 2 ? W2 : W3;
    int N = seg < 2 ? 256 : 128;
    int k = r / N, nn = r - k * N;
    int kt = k >> 5, q = (k & 31) >> 3, jj = k & 7;
    int nt = nn >> 4, ln = q * 16 + (nn & 15);
    int NT = N >> 4;
    Wpb[(size_t)seg * 32768 + (((size_t)(kt * NT + nt)) * 64 + ln) * 8 + jj] = f2bf(W[r]);
}

// ---------- gathers: one wave/node, lane = 2 feats, 8-deep batching ----------
__device__ inline void gather_row(const uint* __restrict__ xb, const int* __restrict__ ep,
                                  int m, int lane, float& ax, float& ay) {
    int j = 0;
    for (; j + 8 <= m; j += 8) {
        int4 s4 = *(const int4*)(ep + j);
        int4 s5 = *(const int4*)(ep + j + 4);
        uint u0 = xb[(size_t)s4.x * 64 + lane];
        uint u1 = xb[(size_t)s4.y * 64 + lane];
        uint u2 = xb[(size_t)s4.z * 64 + lane];
        uint u3 = xb[(size_t)s4.w * 64 + lane];
        uint u4 = xb[(size_t)s5.x * 64 + lane];
        uint u5 = xb[(size_t)s5.y * 64 + lane];
        uint u6 = xb[(size_t)s5.z * 64 + lane];
        uint u7 = xb[(size_t)s5.w * 64 + lane];
        ax += bf2f((ushort)u0) + bf2f((ushort)u1) + bf2f((ushort)u2) + bf2f((ushort)u3) +
              bf2f((ushort)u4) + bf2f((ushort)u5) + bf2f((ushort)u6) + bf2f((ushort)u7);
        ay += bf2f((ushort)(u0 >> 16)) + bf2f((ushort)(u1 >> 16)) +
              bf2f((ushort)(u2 >> 16)) + bf2f((ushort)(u3 >> 16)) +
              bf2f((ushort)(u4 >> 16)) + bf2f((ushort)(u5 >> 16)) +
              bf2f((ushort)(u6 >> 16)) + bf2f((ushort)(u7 >> 16));
    }
    for (; j + 4 <= m; j += 4) {
        int4 s4 = *(const int4*)(ep + j);
        uint u0 = xb[(size_t)s4.x * 64 + lane];
        uint u1 = xb[(size_t)s4.y * 64 + lane];
        uint u2 = xb[(size_t)s4.z * 64 + lane];
        uint u3 = xb[(size_t)s4.w * 64 + lane];
        ax += bf2f((ushort)u0) + bf2f((ushort)u1) + bf2f((ushort)u2) + bf2f((ushort)u3);
        ay += bf2f((ushort)(u0 >> 16)) + bf2f((ushort)(u1 >> 16)) +
              bf2f((ushort)(u2 >> 16)) + bf2f((ushort)(u3 >> 16));
    }
    for (; j < m; ++j) {
        uint u = xb[(size_t)ep[j] * 64 + lane];
        ax += bf2f((ushort)u);
        ay += bf2f((ushort)(u >> 16));
    }
}

// layer1, both branches: blocks [0,gb) = branch a, [gb,2gb) = branch b.
// Output: plain bf16 pairs (uint), same format as xb.
__global__ __launch_bounds__(256) void k_gather_l1(
    const uint* __restrict__ xba, const uint* __restrict__ xbb,
    const int* __restrict__ csr_a, const int* __restrict__ csr_b,
    const int* __restrict__ noff, const float* __restrict__ dinv,
    uint* __restrict__ ta, uint* __restrict__ tb, int n, int gb) {
    int bid = blockIdx.x;
    int br = bid >= gb;
    const uint* xb = br ? xbb : xba;
    const int* csr = br ? csr_b : csr_a;
    const int* no = noff + (size_t)br * (n + 1);
    const float* dv = dinv + (size_t)br * n;
    uint* outp = br ? tb : ta;
    int node = ((bid - (br ? gb : 0)) * 256 + (int)threadIdx.x) >> 6;
    if (node >= n) return;
    node = __builtin_amdgcn_readfirstlane(node);
    const int lane = threadIdx.x & 63;
    int beg = no[node], m = no[node + 1] - beg;
    uint us = xb[(size_t)node * 64 + lane];
    float ax = 0.f, ay = 0.f;
    gather_row(xb, csr + beg, m, lane, ax, ay);
    float di = dv[node];
    uint o = (uint)f2bf(di * (ax + bf2f((ushort)us))) |
             ((uint)f2bf(di * (ay + bf2f((ushort)(us >> 16)))) << 16);
    outp[(size_t)node * 64 + lane] = o;
}

// layer2, BOTH branches + bias; single write pass over out.
__global__ __launch_bounds__(256) void k_gather_l2(
    const uint* __restrict__ hba, const uint* __restrict__ hbb,
    const int* __restrict__ csr_a, const int* __restrict__ csr_b,
    const int* __restrict__ noff, const float* __restrict__ dinv,
    const float* __restrict__ b2, const float* __restrict__ b3,
    float* __restrict__ out, int n) {
    int node = (blockIdx.x * 256 + (int)threadIdx.x) >> 6;
    if (node >= n) return;
    node = __builtin_amdgcn_readfirstlane(node);
    const int lane = threadIdx.x & 63;

    int beg = noff[node], m = noff[node + 1] - beg;
    float ax = 0.f, ay = 0.f;
    gather_row(hba, csr_a + beg, m, lane, ax, ay);
    uint usa = hba[(size_t)node * 64 + lane];
    float da = dinv[node];
    float vx = da * (ax + bf2f((ushort)usa));
    float vy = da * (ay + bf2f((ushort)(usa >> 16)));

    const int* no_b = noff + (n + 1);
    int beg2 = no_b[node], m2 = no_b[node + 1] - beg2;
    float bx = 0.f, by = 0.f;
    gather_row(hbb, csr_b + beg2, m2, lane, bx, by);
    uint usb = hbb[(size_t)node * 64 + lane];
    float db = dinv[n + node];
    vx += db * (bx + bf2f((ushort)usb));
    vy += db * (by + bf2f((ushort)(usb >> 16)));

    const int f = lane * 2;
    float2 o;
    o.x = b2[f] + b3[f] + vx;
    o.y = b2[f + 1] + b3[f + 1] + vy;
    *(float2*)(out + (size_t)node * 128 + f) = o;
}

// ---------- FUSED MLP: h = relu(A@W1+b) -> LDS bf16 -> C = (h@W2)*dinv ----------
// Plain bf16 MFMA. Block = 64 rows, 4 waves, LDS 33.8KB -> 4 blocks/CU.
// Stage1: wave tile 64x64 (cols wave*64 of h[64,256]). Stage2: wave tile 64x32.
// LDS row stride 264 ushort (528B = 33*16B: aligned b128 reads, 2-way bank alias = free).
__global__ __launch_bounds__(256) void k_mlp_fused(
    const ushort* __restrict__ ta, const ushort* __restrict__ tb,
    const ushort* __restrict__ Wpb, const float* __restrict__ b0,
    const float* __restrict__ b1, const float* __restrict__ dinv,
    ushort* __restrict__ oa, ushort* __restrict__ ob, int n) {
    constexpr int LDW = 264;
    __shared__ ushort hs[64 * LDW];  // 33.8 KB
    const int br = blockIdx.y;
    const ushort* Ap  = br ? tb : ta;
    const ushort* W1  = Wpb + (br ? 32768 : 0);
    const ushort* W2  = Wpb + (br ? 3 * 32768 : 2 * 32768);
    const float* bias = br ? b1 : b0;
    const float* dv   = dinv + (br ? n : 0);
    ushort* Cout      = br ? ob : oa;

    const int lane = threadIdx.x & 63;
    const int wave = threadIdx.x >> 6;
    const int l15 = lane & 15;
    const int quad = lane >> 4;
    const int row_blk = blockIdx.x * 64;

    // ---- stage 1: h[64 x 64] at cols wave*64 ----
    {
        f4_t acc[4][4];
#pragma unroll
        for (int a = 0; a < 4; ++a)
#pragma unroll
            for (int b = 0; b < 4; ++b) acc[a][b] = (f4_t){0.f, 0.f, 0.f, 0.f};

#pragma unroll
        for (int kt = 0; kt < 4; ++kt) {
            bf8_t af[4];
#pragma unroll
            for (int mi = 0; mi < 4; ++mi) {
                int row = row_blk + mi * 16 + l15;
                if (row < n)
                    af[mi] = *(const bf8_t*)(Ap + (size_t)row * 128 + kt * 32 + quad * 8);
                else
                    af[mi] = (bf8_t){0, 0, 0, 0, 0, 0, 0, 0};
            }
#pragma unroll
            for (int nj = 0; nj < 4; ++nj) {
                int nt = wave * 4 + nj;
                bf8_t wf = *(const bf8_t*)(W1 + (((size_t)(kt * 16 + nt)) * 64 + lane) * 8);
#pragma unroll
                for (int mi = 0; mi < 4; ++mi)
                    acc[mi][nj] = __builtin_amdgcn_mfma_f32_16x16x32_bf16(af[mi], wf, acc[mi][nj], 0, 0, 0);
            }
        }
        // epilogue 1 -> LDS (bias + relu, bf16)
#pragma unroll
        for (int nj = 0; nj < 4; ++nj) {
            int col = wave * 64 + nj * 16 + l15;
            float bv = bias[col];
#pragma unroll
            for (int mi = 0; mi < 4; ++mi)
#pragma unroll
                for (int r = 0; r < 4; ++r) {
                    int rl = mi * 16 + quad * 4 + r;
                    hs[rl * LDW + col] = f2bf(fmaxf(acc[mi][nj][r] + bv, 0.f));
                }
        }
    }
    __syncthreads();

    // ---- stage 2: C[64 x 32] at cols wave*32 ----
    {
        f4_t acc2[4][2];
#pragma unroll
        for (int a = 0; a < 4; ++a)
#pragma unroll
            for (int b = 0; b < 2; ++b) acc2[a][b] = (f4_t){0.f, 0.f, 0.f, 0.f};

#pragma unroll
        for (int kt = 0; kt < 8; ++kt) {
            bf8_t af[4];
#pragma unroll
            for (int mi = 0; mi < 4; ++mi)
                af[mi] = *(const bf8_t*)&hs[(mi * 16 + l15) * LDW + kt * 32 + quad * 8];
#pragma unroll
            for (int nj = 0; nj < 2; ++nj) {
                int nt = wave * 2 + nj;
                bf8_t wf = *(const bf8_t*)(W2 + (((size_t)(kt * 8 + nt)) * 64 + lane) * 8);
#pragma unroll
                for (int mi = 0; mi < 4; ++mi)
                    acc2[mi][nj] = __builtin_amdgcn_mfma_f32_16x16x32_bf16(af[mi], wf, acc2[mi][nj], 0, 0, 0);
            }
        }
        // epilogue 2: scale by dinv[row], write bf16 g
#pragma unroll
        for (int nj = 0; nj < 2; ++nj) {
            int col = wave * 32 + nj * 16 + l15;
#pragma unroll
            for (int mi = 0; mi < 4; ++mi)
#pragma unroll
                for (int r = 0; r < 4; ++r) {
                    int row = row_blk + mi * 16 + quad * 4 + r;
                    if (row < n)
                        Cout[(size_t)row * 128 + col] = f2bf(acc2[mi][nj][r] * dv[row]);
                }
        }
    }
}

extern "C" void kernel_launch(void* const* d_in, const int* in_sizes, int n_in,
                              void* d_out, int out_size, void* d_ws, size_t ws_size,
                              hipStream_t stream) {
    const float* x    = (const float*)d_in[0];
    const int*   ei_a = (const int*)d_in[1];
    const int*   ei_b = (const int*)d_in[2];
    const float* W0 = (const float*)d_in[3];
    const float* b0 = (const float*)d_in[4];
    const float* W1 = (const float*)d_in[5];
    const float* b1 = (const float*)d_in[6];
    const float* W2 = (const float*)d_in[7];
    const float* b2 = (const float*)d_in[8];
    const float* W3 = (const float*)d_in[9];
    const float* b3 = (const float*)d_in[10];
    float* out = (float*)d_out;

    const int n = in_sizes[0] / 128;  // 50000
    const int e = in_sizes[1] / 2;    // 800000
    const int NB = (n + 63) / 64;     // 782
    const int NW = (e + CHUNK - 1) / CHUNK;  // 196 (<= 256)

    // workspace (~95 MB)
    float*  ws    = (float*)d_ws;
    float*  dinv  = ws;                               // 2n
    uint*   ta    = (uint*)(ws + 2 * (size_t)n);      // 64n (bf16 t128, branch a)
    uint*   tb    = ta + 64 * (size_t)n;              // 64n
    uint*   xba   = tb + 64 * (size_t)n;              // 64n
    uint*   xbb   = xba + 64 * (size_t)n;             // 64n
    uint*   oa    = xbb + 64 * (size_t)n;             // 64n (bf16 g, branch a)
    uint*   ob    = oa + 64 * (size_t)n;              // 64n
    ushort* Wpb   = (ushort*)(ob + 64 * (size_t)n);   // 4*32768 ushort
    int* cnt_mat  = (int*)(Wpb + 4 * 32768);          // 2*NW*NB
    int* wgoff    = cnt_mat + 2 * (size_t)NW * NB;    // 2*NB*NW
    int* btot     = wgoff + 2 * (size_t)NB * NW;      // 2*NB
    int* boff     = btot + 2 * NB;                    // 2*(NB+1)
    int* noff     = boff + 2 * (NB + 1);              // 2*(n+1)
    int* ebuf_a   = noff + 2 * (n + 1);               // e
    int* ebuf_b   = ebuf_a + e;                       // e
    int* csr_a    = ebuf_b + e;                       // e
    int* csr_b    = csr_a + e;                        // e

    const int B = 256;

    // --- CSR build (atomic-free, high-parallelism) ---
    k_p1_hist<<<2 * NW, B, 0, stream>>>(ei_a, ei_b, cnt_mat, e, NB, NW);
    k_p2a<<<2 * NB, B, 0, stream>>>(cnt_mat, wgoff, btot, NB, NW);
    k_p2b<<<1, B, 0, stream>>>(btot, boff, NB, e);
    k_p3_scatter<<<2 * NW, B, 0, stream>>>(ei_a, ei_b, wgoff, boff, ebuf_a, ebuf_b, e, NB, NW);
    k_p4_nodesort<<<2 * NB, B, 0, stream>>>(ebuf_a, ebuf_b, boff, csr_a, csr_b, noff, dinv,
                                            n, e, NB);

    // --- conversions ---
    k_cvt<<<(n * 64 + B - 1) / B, B, 0, stream>>>((const float2*)x, dinv, xba, xbb, n);
    k_pack_all<<<(4 * 32768 + B - 1) / B, B, 0, stream>>>(W0, W1, W2, W3, Wpb);

    const int gb = (n + 3) / 4;
    const int mblocks = (n + 63) / 64;

    // layer-1 aggregation, both branches
    k_gather_l1<<<2 * gb, B, 0, stream>>>(xba, xbb, csr_a, csr_b, noff, dinv, ta, tb, n, gb);

    // fused MLP, both branches
    k_mlp_fused<<<dim3(mblocks, 2), B, 0, stream>>>((const ushort*)ta, (const ushort*)tb,
                                                    Wpb, b0, b1, dinv,
                                                    (ushort*)oa, (ushort*)ob, n);

    // layer-2 aggregation + ensemble sum + bias
    k_gather_l2<<<gb, B, 0, stream>>>(oa, ob, csr_a, csr_b, noff, dinv, b2, b3, out, n);
}

// Round 9
// 289.764 us; speedup vs baseline: 19.7814x; 1.0854x over previous
//
#include <hip/hip_runtime.h>

// GCN ensemble: atomic-free counting-sort CSR (256-node buckets) + FUSED
// (gather_l1 + MLP) kernel + final gather_l2.
// R8 conclusion: gathers are at the random-access roofline (FETCH == per-XCD
// compulsory-fill bound; 3.7 TB/s == 256B-granule ceiling). This round removes
// the ta intermediate entirely: each MLP block's A-rows are exactly the nodes
// gather_l1 would produce for it -> gather into LDS A-tile, barrier, MFMA.
// Math: agg[d] = dinv_d * (sum_s g[s] + g[d]), g = dinv*h.

typedef unsigned int uint;
typedef unsigned short ushort;
typedef __attribute__((ext_vector_type(8))) short bf8_t;
typedef __attribute__((ext_vector_type(4))) float f4_t;

#define CHUNK 4096   // edges per WG in P1/P3; NW = ceil(e/CHUNK) <= 256
#define BKT 256      // nodes per bucket; NB = ceil(n/256) <= 256, needs n < 2^17

__device__ inline ushort f2bf(float f) {
    uint u = __float_as_uint(f);
    return (ushort)((u + 0x7fff + ((u >> 16) & 1)) >> 16);
}
__device__ inline float bf2f(ushort h) { return __uint_as_float(((uint)h) << 16); }

// ---------- P1: per-chunk bucket histogram (LDS), dense writes ----------
__global__ __launch_bounds__(256) void k_p1_hist(
    const int* __restrict__ ei_a, const int* __restrict__ ei_b,
    int* __restrict__ cnt_mat, int e, int NB, int NW) {
    __shared__ int lh[BKT];
    int l = blockIdx.x / NW, w = blockIdx.x % NW;
    const int* dst = (l ? ei_b : ei_a) + e;
    if (threadIdx.x < NB) lh[threadIdx.x] = 0;
    __syncthreads();
    int beg = w * CHUNK, end = min(beg + CHUNK, e);
    for (int j = beg + threadIdx.x; j < end; j += 256) atomicAdd(&lh[dst[j] >> 8], 1);
    __syncthreads();
    int* outp = cnt_mat + ((size_t)l * NW + w) * NB;
    if (threadIdx.x < NB) outp[threadIdx.x] = lh[threadIdx.x];
}

// ---------- P2a: per-bucket exclusive prefix over WGs (one block per bucket) ----------
__global__ __launch_bounds__(256) void k_p2a(const int* __restrict__ cnt_mat,
                                             int* __restrict__ wgoff, int* __restrict__ btot,
                                             int NB, int NW) {
    __shared__ int s[256];
    int which = blockIdx.x;  // 0..2*NB-1
    int l = which / NB, b = which - l * NB;
    int t = threadIdx.x;
    int v = (t < NW) ? cnt_mat[((size_t)l * NW + t) * NB + b] : 0;
    s[t] = v;
    __syncthreads();
    for (int o = 1; o < 256; o <<= 1) {
        int x = 0;
        if (t >= o) x = s[t - o];
        __syncthreads();
        s[t] += x;
        __syncthreads();
    }
    if (t < NW) wgoff[((size_t)l * NB + b) * NW + t] = s[t] - v;
    if (t == 255) btot[which] = s[255];
}

// ---------- P2b: exclusive scan of bucket totals per list (one WG, NB<=256) ----------
__global__ __launch_bounds__(256) void k_p2b(const int* __restrict__ btot,
                                             int* __restrict__ boff, int NB, int e) {
    __shared__ int s[256];
    for (int l = 0; l < 2; ++l) {
        int t = threadIdx.x;
        int v = (t < NB) ? btot[l * NB + t] : 0;
        s[t] = v;
        __syncthreads();
        for (int o = 1; o < 256; o <<= 1) {
            int x = 0;
            if (t >= o) x = s[t - o];
            __syncthreads();
            s[t] += x;
            __syncthreads();
        }
        if (t < NB) boff[l * (NB + 1) + t] = s[t] - v;
        if (t == 0) boff[l * (NB + 1) + NB] = e;
        __syncthreads();
    }
}

// ---------- P3: scatter packed entries into contiguous per-(WG,bucket) segments ----------
__global__ __launch_bounds__(256) void k_p3_scatter(
    const int* __restrict__ ei_a, const int* __restrict__ ei_b,
    const int* __restrict__ wgoff, const int* __restrict__ boff,
    int* __restrict__ ebuf_a, int* __restrict__ ebuf_b, int e, int NB, int NW) {
    __shared__ int base[BKT];
    __shared__ int bump[BKT];
    int l = blockIdx.x / NW, w = blockIdx.x % NW;
    const int* ei = l ? ei_b : ei_a;
    int* ebuf = l ? ebuf_b : ebuf_a;
    if (threadIdx.x < NB) {
        base[threadIdx.x] = boff[l * (NB + 1) + threadIdx.x] +
                            wgoff[((size_t)l * NB + threadIdx.x) * NW + w];
        bump[threadIdx.x] = 0;
    }
    __syncthreads();
    int beg = w * CHUNK, end = min(beg + CHUNK, e);
    for (int j = beg + threadIdx.x; j < end; j += 256) {
        int sv = ei[j], d = ei[e + j];
        int b = d >> 8;
        int pos = base[b] + atomicAdd(&bump[b], 1);
        ebuf[pos] = ((d & 255) << 17) | sv;  // needs src < 2^17
    }
}

// ---------- P4: within-bucket node sort -> final CSR + noff + dinv ----------
__global__ __launch_bounds__(256) void k_p4_nodesort(
    const int* __restrict__ ebuf_a, const int* __restrict__ ebuf_b,
    const int* __restrict__ boff, int* __restrict__ csr_a, int* __restrict__ csr_b,
    int* __restrict__ noff, float* __restrict__ dinv, int n, int e, int NB) {
    __shared__ int hist[256], nstart[256], sc[256];
    int which = blockIdx.x;
    int l = which / NB, b = which - l * NB;
    const int* ebuf = l ? ebuf_b : ebuf_a;
    int* csr = l ? csr_b : csr_a;
    int seg0 = boff[l * (NB + 1) + b], seg1 = boff[l * (NB + 1) + b + 1];
    int t = threadIdx.x;
    hist[t] = 0;
    __syncthreads();
    for (int j = seg0 + t; j < seg1; j += 256) atomicAdd(&hist[ebuf[j] >> 17], 1);
    __syncthreads();
    int v = hist[t];
    sc[t] = v;
    __syncthreads();
    for (int o = 1; o < 256; o <<= 1) {
        int x = 0;
        if (t >= o) x = sc[t - o];
        __syncthreads();
        sc[t] += x;
        __syncthreads();
    }
    nstart[t] = seg0 + sc[t] - v;
    int node = b * BKT + t;
    if (node < n) {
        noff[(size_t)l * (n + 1) + node] = nstart[t];
        dinv[(size_t)l * n + node] = rsqrtf((float)v + 1.0f);
    }
    hist[t] = 0;  // reuse as bump counter
    if (b == NB - 1 && t == 0) noff[(size_t)l * (n + 1) + n] = e;
    __syncthreads();
    for (int j = seg0 + t; j < seg1; j += 256) {
        int pk = ebuf[j];
        int ni = pk >> 17;
        int pos = nstart[ni] + atomicAdd(&hist[ni], 1);
        csr[pos] = pk & 0x1ffff;
    }
}

// ---------- fused cvt (x -> per-branch dinv-scaled bf16) + weight packing ----------
__global__ void k_cvt_pack(const float2* __restrict__ x2, const float* __restrict__ dinv,
                           uint* __restrict__ xba, uint* __restrict__ xbb,
                           const float* __restrict__ W0, const float* __restrict__ W1,
                           const float* __restrict__ W2, const float* __restrict__ W3,
                           ushort* __restrict__ Wpb, int n, int cvtb) {
    if ((int)blockIdx.x < cvtb) {
        int i = blockIdx.x * 256 + threadIdx.x;
        if (i >= n * 64) return;
        int node = i >> 6;
        float da = dinv[node], db = dinv[n + node];
        float2 v = x2[i];
        xba[i] = (uint)f2bf(da * v.x) | ((uint)f2bf(da * v.y) << 16);
        xbb[i] = (uint)f2bf(db * v.x) | ((uint)f2bf(db * v.y) << 16);
    } else {
        int i = (blockIdx.x - cvtb) * 256 + threadIdx.x;
        if (i >= 4 * 32768) return;
        int seg = i >> 15;
        int r = i & 32767;
        const float* W = seg == 0 ? W0 : seg == 1 ? W1 : seg == 2 ? W2 : W3;
        int N = seg < 2 ? 256 : 128;
        int k = r / N, nn = r - k * N;
        int kt = k >> 5, q = (k & 31) >> 3, jj = k & 7;
        int nt = nn >> 4, ln = q * 16 + (nn & 15);
        int NT = N >> 4;
        Wpb[(size_t)seg * 32768 + (((size_t)(kt * NT + nt)) * 64 + ln) * 8 + jj] = f2bf(W[r]);
    }
}

// ---------- gather inner loop: lane = 2 feats, 8-deep batching ----------
__device__ inline void gather_row(const uint* __restrict__ xb, const int* __restrict__ ep,
                                  int m, int lane, float& ax, float& ay) {
    int j = 0;
    for (; j + 8 <= m; j += 8) {
        int4 s4 = *(const int4*)(ep + j);
        int4 s5 = *(const int4*)(ep + j + 4);
        uint u0 = xb[(size_t)s4.x * 64 + lane];
        uint u1 = xb[(size_t)s4.y * 64 + lane];
        uint u2 = xb[(size_t)s4.z * 64 + lane];
        uint u3 = xb[(size_t)s4.w * 64 + lane];
        uint u4 = xb[(size_t)s5.x * 64 + lane];
        uint u5 = xb[(size_t)s5.y * 64 + lane];
        uint u6 = xb[(size_t)s5.z * 64 + lane];
        uint u7 = xb[(size_t)s5.w * 64 + lane];
        ax += bf2f((ushort)u0) + bf2f((ushort)u1) + bf2f((ushort)u2) + bf2f((ushort)u3) +
              bf2f((ushort)u4) + bf2f((ushort)u5) + bf2f((ushort)u6) + bf2f((ushort)u7);
        ay += bf2f((ushort)(u0 >> 16)) + bf2f((ushort)(u1 >> 16)) +
              bf2f((ushort)(u2 >> 16)) + bf2f((ushort)(u3 >> 16)) +
              bf2f((ushort)(u4 >> 16)) + bf2f((ushort)(u5 >> 16)) +
              bf2f((ushort)(u6 >> 16)) + bf2f((ushort)(u7 >> 16));
    }
    for (; j + 4 <= m; j += 4) {
        int4 s4 = *(const int4*)(ep + j);
        uint u0 = xb[(size_t)s4.x * 64 + lane];
        uint u1 = xb[(size_t)s4.y * 64 + lane];
        uint u2 = xb[(size_t)s4.z * 64 + lane];
        uint u3 = xb[(size_t)s4.w * 64 + lane];
        ax += bf2f((ushort)u0) + bf2f((ushort)u1) + bf2f((ushort)u2) + bf2f((ushort)u3);
        ay += bf2f((ushort)(u0 >> 16)) + bf2f((ushort)(u1 >> 16)) +
              bf2f((ushort)(u2 >> 16)) + bf2f((ushort)(u3 >> 16));
    }
    for (; j < m; ++j) {
        uint u = xb[(size_t)ep[j] * 64 + lane];
        ax += bf2f((ushort)u);
        ay += bf2f((ushort)(u >> 16));
    }
}

// ---------- FUSED gather_l1 + MLP ----------
// Block = 32 nodes, 4 waves. Phase 1: each wave gathers 8 nodes' aggregates into
// an LDS A-tile (bf16, 16B-block rotation swizzle: write conflict-free, read <=4-way).
// Phase 2: h = relu(A@W1+b) -> LDS bf16 -> C = (h@W2)*dinv -> global bf16.
// LDS = 8KB A + 16.9KB h = 24.9KB -> 6 blocks/CU (24 waves/CU).
__global__ __launch_bounds__(256) void k_gather_mlp(
    const uint* __restrict__ xba, const uint* __restrict__ xbb,
    const int* __restrict__ csr_a, const int* __restrict__ csr_b,
    const int* __restrict__ noff, const float* __restrict__ dinv,
    const ushort* __restrict__ Wpb, const float* __restrict__ b0,
    const float* __restrict__ b1, ushort* __restrict__ oa, ushort* __restrict__ ob,
    int n, int nblk) {
    constexpr int HW = 264;            // h-tile row stride (ushorts)
    __shared__ uint As32[32 * 64];     // A-tile: 32 rows x 64 dwords (swizzled), 8KB
    __shared__ ushort hs[32 * HW];     // 16.9KB

    int bid = blockIdx.x;
    int br = bid >= nblk;
    int blk = br ? bid - nblk : bid;
    const uint* xb = br ? xbb : xba;
    const int* csr = br ? csr_b : csr_a;
    const int* no = noff + (size_t)br * (n + 1);
    const float* dv = dinv + (size_t)br * n;
    const ushort* W1 = Wpb + (br ? 32768 : 0);
    const ushort* W2 = Wpb + (br ? 3 * 32768 : 2 * 32768);
    const float* bias = br ? b1 : b0;
    ushort* Cout = br ? ob : oa;

    const int lane = threadIdx.x & 63;
    const int wave = threadIdx.x >> 6;
    const int l15 = lane & 15;
    const int quad = lane >> 4;
    const int row0 = blk * 32;

    // ---- phase 1: gather 8 nodes per wave into LDS A-tile ----
    for (int k = 0; k < 8; ++k) {
        int r = wave * 8 + k;  // 0..31
        int node = row0 + r;
        uint o = 0;
        if (node < n) {
            node = __builtin_amdgcn_readfirstlane(node);
            int beg = no[node], m = no[node + 1] - beg;
            float ax = 0.f, ay = 0.f;
            gather_row(xb, csr + beg, m, lane, ax, ay);
            uint us = xb[(size_t)node * 64 + lane];
            float di = dv[node];
            o = (uint)f2bf(di * (ax + bf2f((ushort)us))) |
                ((uint)f2bf(di * (ay + bf2f((ushort)(us >> 16)))) << 16);
        }
        int dw = ((((lane >> 2) + r) & 15) << 2) | (lane & 3);  // rotate 16B blocks by r
        As32[r * 64 + dw] = o;
    }
    __syncthreads();

    // ---- phase 2a: h[32x64 cols @ wave*64] = relu(A@W1 + b) ----
    {
        f4_t acc[2][4];
#pragma unroll
        for (int a = 0; a < 2; ++a)
#pragma unroll
            for (int b = 0; b < 4; ++b) acc[a][b] = (f4_t){0.f, 0.f, 0.f, 0.f};

#pragma unroll
        for (int kt = 0; kt < 4; ++kt) {
            bf8_t af[2];
#pragma unroll
            for (int mi = 0; mi < 2; ++mi) {
                int rr = mi * 16 + l15;
                int blk16 = (kt * 4 + quad + rr) & 15;  // un-rotate
                af[mi] = *(const bf8_t*)&As32[rr * 64 + blk16 * 4];
            }
#pragma unroll
            for (int nj = 0; nj < 4; ++nj) {
                int nt = wave * 4 + nj;
                bf8_t wf = *(const bf8_t*)(W1 + (((size_t)(kt * 16 + nt)) * 64 + lane) * 8);
#pragma unroll
                for (int mi = 0; mi < 2; ++mi)
                    acc[mi][nj] = __builtin_amdgcn_mfma_f32_16x16x32_bf16(af[mi], wf, acc[mi][nj], 0, 0, 0);
            }
        }
#pragma unroll
        for (int nj = 0; nj < 4; ++nj) {
            int col = wave * 64 + nj * 16 + l15;
            float bv = bias[col];
#pragma unroll
            for (int mi = 0; mi < 2; ++mi)
#pragma unroll
                for (int r = 0; r < 4; ++r)
                    hs[(mi * 16 + quad * 4 + r) * HW + col] = f2bf(fmaxf(acc[mi][nj][r] + bv, 0.f));
        }
    }
    __syncthreads();

    // ---- phase 2b: C[32x32 cols @ wave*32] = (h@W2)*dinv ----
    {
        f4_t acc2[2][2];
#pragma unroll
        for (int a = 0; a < 2; ++a)
#pragma unroll
            for (int b = 0; b < 2; ++b) acc2[a][b] = (f4_t){0.f, 0.f, 0.f, 0.f};

#pragma unroll
        for (int kt = 0; kt < 8; ++kt) {
            bf8_t af[2];
#pragma unroll
            for (int mi = 0; mi < 2; ++mi)
                af[mi] = *(const bf8_t*)&hs[(mi * 16 + l15) * HW + kt * 32 + quad * 8];
#pragma unroll
            for (int nj = 0; nj < 2; ++nj) {
                int nt = wave * 2 + nj;
                bf8_t wf = *(const bf8_t*)(W2 + (((size_t)(kt * 8 + nt)) * 64 + lane) * 8);
#pragma unroll
                for (int mi = 0; mi < 2; ++mi)
                    acc2[mi][nj] = __builtin_amdgcn_mfma_f32_16x16x32_bf16(af[mi], wf, acc2[mi][nj], 0, 0, 0);
            }
        }
#pragma unroll
        for (int nj = 0; nj < 2; ++nj) {
            int col = wave * 32 + nj * 16 + l15;
#pragma unroll
            for (int mi = 0; mi < 2; ++mi)
#pragma unroll
                for (int r = 0; r < 4; ++r) {
                    int row = row0 + mi * 16 + quad * 4 + r;
                    if (row < n)
                        Cout[(size_t)row * 128 + col] = f2bf(acc2[mi][nj][r] * dv[row]);
                }
        }
    }
}

// ---------- gather_l2: BOTH branches + bias; single write pass over out ----------
__global__ __launch_bounds__(256) void k_gather_l2(
    const uint* __restrict__ hba, const uint* __restrict__ hbb,
    const int* __restrict__ csr_a, const int* __restrict__ csr_b,
    const int* __restrict__ noff, const float* __restrict__ dinv,
    const float* __restrict__ b2, const float* __restrict__ b3,
    float* __restrict__ out, int n) {
    int node = (blockIdx.x * 256 + (int)threadIdx.x) >> 6;
    if (node >= n) return;
    node = __builtin_amdgcn_readfirstlane(node);
    const int lane = threadIdx.x & 63;

    int beg = noff[node], m = noff[node + 1] - beg;
    float ax = 0.f, ay = 0.f;
    gather_row(hba, csr_a + beg, m, lane, ax, ay);
    uint usa = hba[(size_t)node * 64 + lane];
    float da = dinv[node];
    float vx = da * (ax + bf2f((ushort)usa));
    float vy = da * (ay + bf2f((ushort)(usa >> 16)));

    const int* no_b = noff + (n + 1);
    int beg2 = no_b[node], m2 = no_b[node + 1] - beg2;
    float bx = 0.f, by = 0.f;
    gather_row(hbb, csr_b + beg2, m2, lane, bx, by);
    uint usb = hbb[(size_t)node * 64 + lane];
    float db = dinv[n + node];
    vx += db * (bx + bf2f((ushort)usb));
    vy += db * (by + bf2f((ushort)(usb >> 16)));

    const int f = lane * 2;
    float2 o;
    o.x = b2[f] + b3[f] + vx;
    o.y = b2[f + 1] + b3[f + 1] + vy;
    *(float2*)(out + (size_t)node * 128 + f) = o;
}

extern "C" void kernel_launch(void* const* d_in, const int* in_sizes, int n_in,
                              void* d_out, int out_size, void* d_ws, size_t ws_size,
                              hipStream_t stream) {
    const float* x    = (const float*)d_in[0];
    const int*   ei_a = (const int*)d_in[1];
    const int*   ei_b = (const int*)d_in[2];
    const float* W0 = (const float*)d_in[3];
    const float* b0 = (const float*)d_in[4];
    const float* W1 = (const float*)d_in[5];
    const float* b1 = (const float*)d_in[6];
    const float* W2 = (const float*)d_in[7];
    const float* b2 = (const float*)d_in[8];
    const float* W3 = (const float*)d_in[9];
    const float* b3 = (const float*)d_in[10];
    float* out = (float*)d_out;

    const int n = in_sizes[0] / 128;  // 50000 (< 2^17)
    const int e = in_sizes[1] / 2;    // 800000
    const int NB = (n + BKT - 1) / BKT;      // 196 (<= 256)
    const int NW = (e + CHUNK - 1) / CHUNK;  // 196 (<= 256)

    // workspace (~92 MB)
    float*  ws   = (float*)d_ws;
    float*  dinv = ws;                                // 2n
    uint*   xba  = (uint*)(ws + 2 * (size_t)n);       // 64n
    uint*   xbb  = xba + 64 * (size_t)n;              // 64n
    uint*   oa   = xbb + 64 * (size_t)n;              // 64n (bf16 g, branch a)
    uint*   ob   = oa + 64 * (size_t)n;               // 64n
    ushort* Wpb  = (ushort*)(ob + 64 * (size_t)n);    // 4*32768 ushort
    int* cnt_mat = (int*)(Wpb + 4 * 32768);           // 2*NW*NB
    int* wgoff   = cnt_mat + 2 * (size_t)NW * NB;     // 2*NB*NW
    int* btot    = wgoff + 2 * (size_t)NB * NW;       // 2*NB
    int* boff    = btot + 2 * NB;                     // 2*(NB+1)
    int* noff    = boff + 2 * (NB + 1);               // 2*(n+1)
    int* ebuf_a  = noff + 2 * (n + 1);                // e
    int* ebuf_b  = ebuf_a + e;                        // e
    int* csr_a   = ebuf_b + e;                        // e
    int* csr_b   = csr_a + e;                         // e

    const int B = 256;

    // --- CSR build (atomic-free) ---
    k_p1_hist<<<2 * NW, B, 0, stream>>>(ei_a, ei_b, cnt_mat, e, NB, NW);
    k_p2a<<<2 * NB, B, 0, stream>>>(cnt_mat, wgoff, btot, NB, NW);
    k_p2b<<<1, B, 0, stream>>>(btot, boff, NB, e);
    k_p3_scatter<<<2 * NW, B, 0, stream>>>(ei_a, ei_b, wgoff, boff, ebuf_a, ebuf_b, e, NB, NW);
    k_p4_nodesort<<<2 * NB, B, 0, stream>>>(ebuf_a, ebuf_b, boff, csr_a, csr_b, noff, dinv,
                                            n, e, NB);

    // --- conversions (fused cvt + weight pack) ---
    const int cvtb = (n * 64 + B - 1) / B;
    const int packb = (4 * 32768 + B - 1) / B;
    k_cvt_pack<<<cvtb + packb, B, 0, stream>>>((const float2*)x, dinv, xba, xbb,
                                               W0, W1, W2, W3, Wpb, n, cvtb);

    // --- fused layer-1 gather + MLP, both branches ---
    const int nblk = (n + 31) / 32;
    k_gather_mlp<<<2 * nblk, B, 0, stream>>>(xba, xbb, csr_a, csr_b, noff, dinv, Wpb,
                                             b0, b1, (ushort*)oa, (ushort*)ob, n, nblk);

    // --- layer-2 aggregation + ensemble sum + bias ---
    const int gb = (n + 3) / 4;
    k_gather_l2<<<gb, B, 0, stream>>>(oa, ob, csr_a, csr_b, noff, dinv, b2, b3, out, n);
}